// Round 2
// baseline (970.916 us; speedup 1.0000x reference)
//
#include <hip/hip_runtime.h>

typedef unsigned short u16;
typedef unsigned int   u32;
typedef __attribute__((ext_vector_type(8))) short bf16x8;
typedef __attribute__((ext_vector_type(4))) float f32x4;

constexpr int B_ = 4, S_ = 2048, P_ = 32, D_ = 512, H_ = 8, L_ = 2, DFF_ = 2048;
constexpr int BS_ = B_ * S_;            // 8192 token rows
constexpr float SCALE_ = 0.125f;        // 1/sqrt(64)

__device__ __forceinline__ u16 f2bf(float f) {
    u32 u = __float_as_uint(f);
    u += 0x7fffu + ((u >> 16) & 1u);    // round-to-nearest-even
    return (u16)(u >> 16);
}

// ---------------------------------------------------------------- weight transpose
// Wt[n*K + k] = bf16(W[k*N + n])
__global__ __launch_bounds__(256)
void wtrans_kernel(const float* __restrict__ W, u16* __restrict__ Wt, int K, int N)
{
    __shared__ float tile[32][33];
    const int n0 = blockIdx.x * 32, k0 = blockIdx.y * 32;
    const int t = threadIdx.x;
#pragma unroll
    for (int i = 0; i < 4; i++) {
        int lin = i * 256 + t;
        int r = lin >> 5, c = lin & 31;
        tile[r][c] = W[(size_t)(k0 + r) * N + n0 + c];
    }
    __syncthreads();
#pragma unroll
    for (int i = 0; i < 4; i++) {
        int lin = i * 256 + t;
        int r = lin >> 5, c = lin & 31;
        Wt[(size_t)(n0 + r) * K + k0 + c] = f2bf(tile[c][r]);
    }
}

// ---------------------------------------------------------------- rope tables
__global__ __launch_bounds__(256)
void rope_table_kernel(float* __restrict__ rc, float* __restrict__ rs)
{
    int idx = blockIdx.x * 256 + threadIdx.x;   // S_*32 = 65536
    int j = idx & 31, tpos = idx >> 5;
    float inv = __expf(-(float)j * 0.28782313662425572f);  // 10000^(-j/32)
    float ang = (float)tpos * inv;
    rc[idx] = cosf(ang);
    rs[idx] = sinf(ang);
}

// ---------------------------------------------------------------- GEMM: C = A(f32,MxK) @ Bt^T(bf16,NxK) + bias, ACT=1 -> exact GELU
template<int ACT>
__global__ __launch_bounds__(256)
void gemm_kernel(const float* __restrict__ A, const u16* __restrict__ Bt,
                 const float* __restrict__ bias, float* __restrict__ C,
                 int M, int N, int K)
{
    constexpr int LDT = 40;                // padded row stride (bank-conflict relief)
    __shared__ u16 As[128 * LDT];
    __shared__ u16 Bs[128 * LDT];
    const int t = threadIdx.x;
    const int m0 = blockIdx.y * 128, n0 = blockIdx.x * 128;
    const int lane = t & 63, w = t >> 6;
    const int wr = w >> 1, wc = w & 1;
    const int l15 = lane & 15, lhi = lane >> 4;

    f32x4 acc[4][4];
#pragma unroll
    for (int i = 0; i < 4; i++)
#pragma unroll
        for (int j = 0; j < 4; j++)
#pragma unroll
            for (int r = 0; r < 4; r++) acc[i][j][r] = 0.f;

    for (int kt = 0; kt < K; kt += 32) {
        // stage A: 128x32 f32 -> bf16 (RTNE)
#pragma unroll
        for (int i = 0; i < 4; i++) {
            int lin = i * 256 + t;                  // 1024 float4s
            int r = lin >> 3, c4 = (lin & 7) << 2;
            float4 f = *reinterpret_cast<const float4*>(A + (size_t)(m0 + r) * K + kt + c4);
            uint2 pk;
            pk.x = (u32)f2bf(f.x) | ((u32)f2bf(f.y) << 16);
            pk.y = (u32)f2bf(f.z) | ((u32)f2bf(f.w) << 16);
            *reinterpret_cast<uint2*>(&As[r * LDT + c4]) = pk;
        }
        // stage B: 128 rows of Bt (already bf16, [N][K])
#pragma unroll
        for (int i = 0; i < 2; i++) {
            int lin = i * 256 + t;                  // 512 uint4s (8 bf16 each)
            int r = lin >> 2, c8 = (lin & 3) << 3;
            uint4 u = *reinterpret_cast<const uint4*>(Bt + (size_t)(n0 + r) * K + kt + c8);
            *reinterpret_cast<uint4*>(&Bs[r * LDT + c8]) = u;
        }
        __syncthreads();
        bf16x8 af[4], bfv[4];
#pragma unroll
        for (int mi = 0; mi < 4; mi++)
            af[mi] = *reinterpret_cast<const bf16x8*>(&As[(wr * 64 + mi * 16 + l15) * LDT + lhi * 8]);
#pragma unroll
        for (int ni = 0; ni < 4; ni++)
            bfv[ni] = *reinterpret_cast<const bf16x8*>(&Bs[(wc * 64 + ni * 16 + l15) * LDT + lhi * 8]);
#pragma unroll
        for (int mi = 0; mi < 4; mi++)
#pragma unroll
            for (int ni = 0; ni < 4; ni++)
                acc[mi][ni] = __builtin_amdgcn_mfma_f32_16x16x32_bf16(af[mi], bfv[ni], acc[mi][ni], 0, 0, 0);
        __syncthreads();
    }
    float bb[4];
#pragma unroll
    for (int ni = 0; ni < 4; ni++) bb[ni] = bias[n0 + wc * 64 + ni * 16 + l15];
#pragma unroll
    for (int mi = 0; mi < 4; mi++) {
        int row = m0 + wr * 64 + mi * 16 + lhi * 4;
#pragma unroll
        for (int ni = 0; ni < 4; ni++) {
            int col = n0 + wc * 64 + ni * 16 + l15;
#pragma unroll
            for (int r = 0; r < 4; r++) {
                float v = acc[mi][ni][r] + bb[ni];
                if (ACT == 1) v = 0.5f * v * (1.0f + erff(v * 0.70710678118654752f));
                C[(size_t)(row + r) * N + col] = v;
            }
        }
    }
}

// ---------------------------------------------------------------- RoPE + layout + bf16: src f32 [b,s,h*64+d] -> dst bf16 [b,h,s,64]
__global__ __launch_bounds__(256)
void rope_apply_kernel(const float* __restrict__ src, const float* __restrict__ rc,
                       const float* __restrict__ rs, u16* __restrict__ dst)
{
    int idx = blockIdx.x * 256 + threadIdx.x;      // 2^21 pairs
    int i  = idx & 31;
    int s  = (idx >> 5) & (S_ - 1);
    int bh = idx >> 16;
    int b = bh >> 3, hh = bh & 7;
    int f = (2 * i) & 31;
    float c = rc[s * 32 + f], sn = rs[s * 32 + f];
    const float* p = src + (size_t)(b * S_ + s) * D_ + hh * 64 + 2 * i;
    float x1 = p[0], x2 = p[1];
    u16* q = dst + ((size_t)bh * S_ + s) * 64 + 2 * i;
    q[0] = f2bf(x1 * c - x2 * sn);
    q[1] = f2bf(x1 * sn + x2 * c);
}

// ---------------------------------------------------------------- V transpose: f32 [b,s,h*64+d] -> bf16 [b,h,d,s]
__global__ __launch_bounds__(256)
void vtrans_kernel(const float* __restrict__ vin, u16* __restrict__ vout)
{
    __shared__ u16 tile[64][72];
    const int bh = blockIdx.y, b = bh >> 3, hh = bh & 7;
    const int s0 = blockIdx.x * 64;
    const int t = threadIdx.x;
#pragma unroll
    for (int i = 0; i < 4; i++) {
        int lin = i * 256 + t;
        int r = lin >> 4, c4 = (lin & 15) << 2;
        float4 f = *reinterpret_cast<const float4*>(vin + (size_t)(b * S_ + s0 + r) * D_ + hh * 64 + c4);
        tile[r][c4 + 0] = f2bf(f.x);
        tile[r][c4 + 1] = f2bf(f.y);
        tile[r][c4 + 2] = f2bf(f.z);
        tile[r][c4 + 3] = f2bf(f.w);
    }
    __syncthreads();
#pragma unroll
    for (int i = 0; i < 4; i++) {
        int lin = i * 256 + t;
        int d = lin >> 4, c4 = (lin & 15) << 2;
        uint2 pk;
        pk.x = (u32)tile[c4 + 0][d] | ((u32)tile[c4 + 1][d] << 16);
        pk.y = (u32)tile[c4 + 2][d] | ((u32)tile[c4 + 3][d] << 16);
        *reinterpret_cast<uint2*>(vout + ((size_t)bh * 64 + d) * S_ + s0 + c4) = pk;
    }
}

// ---------------------------------------------------------------- flash attention, 1 wave per 32 Q rows
__global__ __launch_bounds__(64)
void attn_kernel(const u16* __restrict__ qb, const u16* __restrict__ kb,
                 const u16* __restrict__ vt, const int* __restrict__ vid,
                 const float* __restrict__ maskp,
                 const float* __restrict__ usame, const float* __restrict__ ucross,
                 float* __restrict__ o)
{
    __shared__ u16 P[32 * 40];
    const int bh = blockIdx.y;
    const int b = bh >> 3, hh = bh & 7;
    const int q0 = blockIdx.x * 32;
    const int lane = threadIdx.x;
    const int l15 = lane & 15, lhi = lane >> 4;
    const u16* qp = qb + (size_t)bh * S_ * 64;
    const u16* kp = kb + (size_t)bh * S_ * 64;
    const u16* vp = vt + (size_t)bh * 64 * S_;
    const float us = usame[hh], uc = ucross[hh];

    bf16x8 qfr[2][2];
#pragma unroll
    for (int mi = 0; mi < 2; mi++)
#pragma unroll
        for (int kk = 0; kk < 2; kk++)
            qfr[mi][kk] = *reinterpret_cast<const bf16x8*>(
                qp + (size_t)(q0 + mi * 16 + l15) * 64 + kk * 32 + lhi * 8);

    int vq[2][4];
#pragma unroll
    for (int mi = 0; mi < 2; mi++)
#pragma unroll
        for (int r = 0; r < 4; r++)
            vq[mi][r] = vid[b * S_ + q0 + mi * 16 + lhi * 4 + r];

    float mrow[2][4], lrow[2][4];
    f32x4 oacc[2][4];
#pragma unroll
    for (int mi = 0; mi < 2; mi++)
#pragma unroll
        for (int r = 0; r < 4; r++) { mrow[mi][r] = -1e30f; lrow[mi][r] = 0.f; }
#pragma unroll
    for (int mi = 0; mi < 2; mi++)
#pragma unroll
        for (int nd = 0; nd < 4; nd++)
#pragma unroll
            for (int r = 0; r < 4; r++) oacc[mi][nd][r] = 0.f;

    for (int kv0 = 0; kv0 < S_; kv0 += 32) {
        bf16x8 kfr[2][2];
#pragma unroll
        for (int ni = 0; ni < 2; ni++)
#pragma unroll
            for (int kk = 0; kk < 2; kk++)
                kfr[ni][kk] = *reinterpret_cast<const bf16x8*>(
                    kp + (size_t)(kv0 + ni * 16 + l15) * 64 + kk * 32 + lhi * 8);

        f32x4 sacc[2][2];
#pragma unroll
        for (int mi = 0; mi < 2; mi++)
#pragma unroll
            for (int ni = 0; ni < 2; ni++) {
#pragma unroll
                for (int r = 0; r < 4; r++) sacc[mi][ni][r] = 0.f;
                sacc[mi][ni] = __builtin_amdgcn_mfma_f32_16x16x32_bf16(qfr[mi][0], kfr[ni][0], sacc[mi][ni], 0, 0, 0);
                sacc[mi][ni] = __builtin_amdgcn_mfma_f32_16x16x32_bf16(qfr[mi][1], kfr[ni][1], sacc[mi][ni], 0, 0, 0);
            }

        int vk[2]; float madd[2];
#pragma unroll
        for (int ni = 0; ni < 2; ni++) {
            int kvp = kv0 + ni * 16 + l15;
            vk[ni] = vid[b * S_ + kvp];
            madd[ni] = (1.0f - maskp[b * S_ + kvp]) * -1e9f;
        }

        float alpha[2][4];
#pragma unroll
        for (int mi = 0; mi < 2; mi++) {
#pragma unroll
            for (int r = 0; r < 4; r++) {
#pragma unroll
                for (int ni = 0; ni < 2; ni++) {
                    float bias = (vq[mi][r] == vk[ni]) ? us : uc;
                    sacc[mi][ni][r] = sacc[mi][ni][r] * SCALE_ + bias + madd[ni];
                }
                float tm = fmaxf(sacc[mi][0][r], sacc[mi][1][r]);
                tm = fmaxf(tm, __shfl_xor(tm, 1));
                tm = fmaxf(tm, __shfl_xor(tm, 2));
                tm = fmaxf(tm, __shfl_xor(tm, 4));
                tm = fmaxf(tm, __shfl_xor(tm, 8));
                float mnew = fmaxf(mrow[mi][r], tm);
                alpha[mi][r] = __expf(mrow[mi][r] - mnew);
                mrow[mi][r] = mnew;
                float p0 = __expf(sacc[mi][0][r] - mnew);
                float p1 = __expf(sacc[mi][1][r] - mnew);
                sacc[mi][0][r] = p0; sacc[mi][1][r] = p1;
                float rsum = p0 + p1;
                rsum += __shfl_xor(rsum, 1);
                rsum += __shfl_xor(rsum, 2);
                rsum += __shfl_xor(rsum, 4);
                rsum += __shfl_xor(rsum, 8);
                lrow[mi][r] = lrow[mi][r] * alpha[mi][r] + rsum;
            }
        }
        // P (C-layout) -> LDS -> A-layout fragments
#pragma unroll
        for (int mi = 0; mi < 2; mi++)
#pragma unroll
            for (int ni = 0; ni < 2; ni++)
#pragma unroll
                for (int r = 0; r < 4; r++)
                    P[(mi * 16 + lhi * 4 + r) * 40 + ni * 16 + l15] = f2bf(sacc[mi][ni][r]);
#pragma unroll
        for (int mi = 0; mi < 2; mi++)
#pragma unroll
            for (int nd = 0; nd < 4; nd++)
#pragma unroll
                for (int r = 0; r < 4; r++) oacc[mi][nd][r] *= alpha[mi][r];

        bf16x8 pa[2];
#pragma unroll
        for (int mi = 0; mi < 2; mi++)
            pa[mi] = *reinterpret_cast<const bf16x8*>(&P[(mi * 16 + l15) * 40 + lhi * 8]);

        bf16x8 vfr[4];
#pragma unroll
        for (int nd = 0; nd < 4; nd++)
            vfr[nd] = *reinterpret_cast<const bf16x8*>(vp + (size_t)(nd * 16 + l15) * S_ + kv0 + lhi * 8);
#pragma unroll
        for (int mi = 0; mi < 2; mi++)
#pragma unroll
            for (int nd = 0; nd < 4; nd++)
                oacc[mi][nd] = __builtin_amdgcn_mfma_f32_16x16x32_bf16(pa[mi], vfr[nd], oacc[mi][nd], 0, 0, 0);
    }
#pragma unroll
    for (int mi = 0; mi < 2; mi++)
#pragma unroll
        for (int r = 0; r < 4; r++) {
            float inv = 1.0f / lrow[mi][r];
            int row = q0 + mi * 16 + lhi * 4 + r;
#pragma unroll
            for (int nd = 0; nd < 4; nd++) {
                int col = hh * 64 + nd * 16 + l15;
                o[(size_t)(b * S_ + row) * D_ + col] = oacc[mi][nd][r] * inv;
            }
        }
}

// ---------------------------------------------------------------- LayerNorm: h = LN(h + t)*g + be, one wave per row
__global__ __launch_bounds__(64)
void ln_kernel(float* h, const float* __restrict__ tbuf,
               const float* __restrict__ g, const float* __restrict__ be)
{
    const int row = blockIdx.x;
    const int lane = threadIdx.x;
    float* hp = h + (size_t)row * D_;
    const float* tp = tbuf + (size_t)row * D_;
    float x[8];
    float s = 0.f, s2 = 0.f;
#pragma unroll
    for (int i = 0; i < 2; i++) {
        float4 a = *reinterpret_cast<const float4*>(hp + lane * 8 + i * 4);
        float4 c = *reinterpret_cast<const float4*>(tp + lane * 8 + i * 4);
        x[i * 4 + 0] = a.x + c.x; x[i * 4 + 1] = a.y + c.y;
        x[i * 4 + 2] = a.z + c.z; x[i * 4 + 3] = a.w + c.w;
    }
#pragma unroll
    for (int j = 0; j < 8; j++) { s += x[j]; s2 += x[j] * x[j]; }
#pragma unroll
    for (int m = 1; m <= 32; m <<= 1) { s += __shfl_xor(s, m); s2 += __shfl_xor(s2, m); }
    float mean = s * (1.0f / 512.0f);
    float var = s2 * (1.0f / 512.0f) - mean * mean;
    float rstd = rsqrtf(var + 1e-5f);
#pragma unroll
    for (int i = 0; i < 2; i++) {
        int c0 = lane * 8 + i * 4;
        float4 outv;
        outv.x = (x[i * 4 + 0] - mean) * rstd * g[c0 + 0] + be[c0 + 0];
        outv.y = (x[i * 4 + 1] - mean) * rstd * g[c0 + 1] + be[c0 + 1];
        outv.z = (x[i * 4 + 2] - mean) * rstd * g[c0 + 2] + be[c0 + 2];
        outv.w = (x[i * 4 + 3] - mean) * rstd * g[c0 + 3] + be[c0 + 3];
        *reinterpret_cast<float4*>(hp + c0) = outv;
    }
}

// ---------------------------------------------------------------- head: out = h @ Wh + bh  (f32, N=32)
__global__ __launch_bounds__(256)
void head_kernel(const float* __restrict__ h, const float* __restrict__ Wh,
                 const float* __restrict__ bhv, float* __restrict__ out)
{
    const int t = threadIdx.x;
    const int p = t & 31, sub = t >> 5;
    const int row = blockIdx.x * 8 + sub;
    const float* hp = h + (size_t)row * D_;
    float acc = 0.f;
#pragma unroll 8
    for (int k = 0; k < D_; k++) acc = fmaf(hp[k], Wh[k * 32 + p], acc);
    out[(size_t)row * 32 + p] = acc + bhv[p];
}

// ---------------------------------------------------------------- launch
extern "C" void kernel_launch(void* const* d_in, const int* in_sizes, int n_in,
                              void* d_out, int out_size, void* d_ws, size_t ws_size,
                              hipStream_t stream)
{
    (void)in_sizes; (void)n_in; (void)out_size; (void)ws_size;
    const float* x     = (const float*)d_in[0];
    const int*   vid   = (const int*)d_in[1];
    const float* maskp = (const float*)d_in[2];
    const float* Wpe   = (const float*)d_in[3];
    const float* bpe   = (const float*)d_in[4];
    const float* Wq    = (const float*)d_in[5];
    const float* bq    = (const float*)d_in[6];
    const float* Wk    = (const float*)d_in[7];
    const float* bk    = (const float*)d_in[8];
    const float* Wv    = (const float*)d_in[9];
    const float* bv    = (const float*)d_in[10];
    const float* Wo    = (const float*)d_in[11];
    const float* bo    = (const float*)d_in[12];
    const float* usame = (const float*)d_in[13];
    const float* ucros = (const float*)d_in[14];
    const float* g1    = (const float*)d_in[15];
    const float* be1   = (const float*)d_in[16];
    const float* W1    = (const float*)d_in[17];
    const float* b1f   = (const float*)d_in[18];
    const float* W2    = (const float*)d_in[19];
    const float* b2f   = (const float*)d_in[20];
    const float* g2    = (const float*)d_in[21];
    const float* be2   = (const float*)d_in[22];
    const float* Whd   = (const float*)d_in[23];
    const float* bhd   = (const float*)d_in[24];

    constexpr size_t MB = 1024ull * 1024ull;
    char* ws = (char*)d_ws;
    float* h   = (float*)(ws + 0);
    float* qf  = (float*)(ws + 16 * MB);
    float* kf  = (float*)(ws + 32 * MB);
    float* vf  = (float*)(ws + 48 * MB);
    u16*   qbb = (u16*)(ws + 64 * MB);
    u16*   kbb = (u16*)(ws + 72 * MB);
    u16*   vtb = (u16*)(ws + 80 * MB);
    float* ob  = (float*)(ws + 88 * MB);
    float* tb  = (float*)(ws + 104 * MB);
    float* fb  = qf;                       // FFN intermediate overlays q/k/v/qb/kb (16..80 MB)
    float* rc  = (float*)(ws + 120 * MB);
    float* rs  = (float*)(ws + 120 * MB + 256 * 1024);
    u16*   wt  = (u16*)(ws + 121 * MB);

    u16* wpe_t = wt;
    auto lwt = [&](int l, int which) -> u16* {
        u16* base = wt + 16384 + (size_t)l * 3145728;
        const size_t offs[6] = {0, 262144, 524288, 786432, 1048576, 2097152};
        return base + offs[which];
    };

    // weight transposes (f32 -> bf16 [N][K])
    wtrans_kernel<<<dim3(16, 1), 256, 0, stream>>>(Wpe, wpe_t, 32, 512);
    for (int l = 0; l < L_; l++) {
        wtrans_kernel<<<dim3(16, 16), 256, 0, stream>>>(Wq + (size_t)l * 262144, lwt(l, 0), 512, 512);
        wtrans_kernel<<<dim3(16, 16), 256, 0, stream>>>(Wk + (size_t)l * 262144, lwt(l, 1), 512, 512);
        wtrans_kernel<<<dim3(16, 16), 256, 0, stream>>>(Wv + (size_t)l * 262144, lwt(l, 2), 512, 512);
        wtrans_kernel<<<dim3(16, 16), 256, 0, stream>>>(Wo + (size_t)l * 262144, lwt(l, 3), 512, 512);
        wtrans_kernel<<<dim3(64, 16), 256, 0, stream>>>(W1 + (size_t)l * 1048576, lwt(l, 4), 512, 2048);
        wtrans_kernel<<<dim3(16, 64), 256, 0, stream>>>(W2 + (size_t)l * 1048576, lwt(l, 5), 2048, 512);
    }
    rope_table_kernel<<<256, 256, 0, stream>>>(rc, rs);

    // embed: h = x @ W_pe + b_pe
    gemm_kernel<0><<<dim3(4, 64), 256, 0, stream>>>(x, wpe_t, bpe, h, BS_, 512, 32);

    for (int l = 0; l < L_; l++) {
        gemm_kernel<0><<<dim3(4, 64), 256, 0, stream>>>(h, lwt(l, 0), bq + l * 512, qf, BS_, 512, 512);
        gemm_kernel<0><<<dim3(4, 64), 256, 0, stream>>>(h, lwt(l, 1), bk + l * 512, kf, BS_, 512, 512);
        gemm_kernel<0><<<dim3(4, 64), 256, 0, stream>>>(h, lwt(l, 2), bv + l * 512, vf, BS_, 512, 512);
        rope_apply_kernel<<<8192, 256, 0, stream>>>(qf, rc, rs, qbb);
        rope_apply_kernel<<<8192, 256, 0, stream>>>(kf, rc, rs, kbb);
        vtrans_kernel<<<dim3(32, 32), 256, 0, stream>>>(vf, vtb);
        attn_kernel<<<dim3(64, 32), 64, 0, stream>>>(qbb, kbb, vtb, vid, maskp,
                                                     usame + l * H_, ucros + l * H_, ob);
        gemm_kernel<0><<<dim3(4, 64), 256, 0, stream>>>(ob, lwt(l, 3), bo + l * 512, tb, BS_, 512, 512);
        ln_kernel<<<8192, 64, 0, stream>>>(h, tb, g1 + l * 512, be1 + l * 512);
        gemm_kernel<1><<<dim3(16, 64), 256, 0, stream>>>(h, lwt(l, 4), b1f + l * 2048, fb, BS_, 2048, 512);
        gemm_kernel<0><<<dim3(4, 64), 256, 0, stream>>>(fb, lwt(l, 5), b2f + l * 512, tb, BS_, 512, 2048);
        ln_kernel<<<8192, 64, 0, stream>>>(h, tb, g2 + l * 512, be2 + l * 512);
    }
    head_kernel<<<1024, 256, 0, stream>>>(h, Whd, bhd, (float*)d_out);
}

// Round 3
// 783.942 us; speedup vs baseline: 1.2385x; 1.2385x over previous
//
#include <hip/hip_runtime.h>

typedef unsigned short u16;
typedef unsigned int   u32;
typedef __attribute__((ext_vector_type(8))) short bf16x8;
typedef __attribute__((ext_vector_type(4))) short bf16x4;
typedef __attribute__((ext_vector_type(4))) float f32x4;
typedef __attribute__((ext_vector_type(4))) int   i32x4;

constexpr int B_ = 4, S_ = 2048, D_ = 512, H_ = 8, L_ = 2, DFF_ = 2048;
constexpr int BS_ = B_ * S_;            // 8192 token rows
constexpr float SCALE_ = 0.125f;        // 1/sqrt(64)

__device__ __forceinline__ u16 f2bf(float f) {
    u32 u = __float_as_uint(f);
    u += 0x7fffu + ((u >> 16) & 1u);    // RTNE
    return (u16)(u >> 16);
}
__device__ __forceinline__ float bf2f(u16 u) {
    return __uint_as_float(((u32)u) << 16);
}
__device__ __forceinline__ u32 cvt_pk_bf16(float lo, float hi) {
    u32 d;
    asm volatile("v_cvt_pk_bf16_f32 %0, %1, %2" : "=v"(d) : "v"(lo), "v"(hi));
    return d;
}

// ---------------------------------------------------------------- weight transpose: Wt[n*K+k] = bf16(W[k*N+n])
__global__ __launch_bounds__(256)
void wtrans_kernel(const float* __restrict__ W, u16* __restrict__ Wt, int K, int N)
{
    __shared__ float tile[32][33];
    const int n0 = blockIdx.x * 32, k0 = blockIdx.y * 32;
    const int t = threadIdx.x;
#pragma unroll
    for (int i = 0; i < 4; i++) {
        int lin = i * 256 + t;
        int r = lin >> 5, c = lin & 31;
        tile[r][c] = W[(size_t)(k0 + r) * N + n0 + c];
    }
    __syncthreads();
#pragma unroll
    for (int i = 0; i < 4; i++) {
        int lin = i * 256 + t;
        int r = lin >> 5, c = lin & 31;
        Wt[(size_t)(n0 + r) * K + k0 + c] = f2bf(tile[c][r]);
    }
}

// ---------------------------------------------------------------- f32 -> bf16 bulk convert (for x)
__global__ __launch_bounds__(256)
void f2b_kernel(const float* __restrict__ in, u16* __restrict__ out, int n4)
{
    int i = blockIdx.x * 256 + threadIdx.x;
    if (i < n4) {
        float4 f = *reinterpret_cast<const float4*>(in + (size_t)i * 4);
        uint2 pk;
        pk.x = (u32)f2bf(f.x) | ((u32)f2bf(f.y) << 16);
        pk.y = (u32)f2bf(f.z) | ((u32)f2bf(f.w) << 16);
        *reinterpret_cast<uint2*>(out + (size_t)i * 4) = pk;
    }
}

// ---------------------------------------------------------------- bias concat for fused QKV
__global__ __launch_bounds__(256)
void bcat_kernel(const float* __restrict__ bq, const float* __restrict__ bk,
                 const float* __restrict__ bv, float* __restrict__ o)
{
    int idx = blockIdx.x * 256 + threadIdx.x;
    if (idx < L_ * 1536) {
        int l = idx / 1536, i = idx % 1536;
        float v = (i < 512) ? bq[l * 512 + i]
                : (i < 1024) ? bk[l * 512 + i - 512]
                             : bv[l * 512 + i - 1024];
        o[idx] = v;
    }
}

// ---------------------------------------------------------------- rope tables (f32, [s][32] for cos/sin)
__global__ __launch_bounds__(256)
void rope_table_kernel(float* __restrict__ rc, float* __restrict__ rs)
{
    int idx = blockIdx.x * 256 + threadIdx.x;   // S_*32 = 65536
    int j = idx & 31, tpos = idx >> 5;
    float inv = __expf(-(float)j * 0.28782313662425572f);  // 10000^(-j/32)
    float ang = (float)tpos * inv;
    rc[idx] = cosf(ang);
    rs[idx] = sinf(ang);
}

// ---------------------------------------------------------------- GEMM: C(bf16) = A(bf16,MxK,lda) @ Bt^T(bf16,NxK) + bias
// ACT=1: exact GELU.  ROPE=1 (BN=128, N=1536): fused rope + [b,h,s,d] relayout for q/k, v passthrough.
template<int ACT, int BN, int ROPE>
__global__ __launch_bounds__(256)
void gemm_kernel(const u16* __restrict__ A, const u16* __restrict__ Bt,
                 const float* __restrict__ bias, u16* __restrict__ C,
                 int M, int N, int K, int lda,
                 u16* __restrict__ qd, u16* __restrict__ kd, u16* __restrict__ vd,
                 const float* __restrict__ rc, const float* __restrict__ rs)
{
    constexpr int LDT = 40;                // padded u16 row stride
    constexpr int NI = BN / 32;
    __shared__ u16 As[128 * LDT];
    __shared__ u16 Bs[BN * LDT];
    const int t = threadIdx.x;
    const int m0 = blockIdx.y * 128, n0 = blockIdx.x * BN;
    const int lane = t & 63, w = t >> 6;
    const int wr = w >> 1, wc = w & 1;
    const int l15 = lane & 15, lhi = lane >> 4;

    f32x4 acc[4][NI];
#pragma unroll
    for (int i = 0; i < 4; i++)
#pragma unroll
        for (int j = 0; j < NI; j++)
#pragma unroll
            for (int r = 0; r < 4; r++) acc[i][j][r] = 0.f;

    for (int kt = 0; kt < K; kt += 32) {
#pragma unroll
        for (int i = 0; i < 2; i++) {                 // A: 128x32 u16 = 512 chunks
            int lin = i * 256 + t;
            int r = lin >> 2, c8 = (lin & 3) << 3;
            *reinterpret_cast<bf16x8*>(&As[r * LDT + c8]) =
                *reinterpret_cast<const bf16x8*>(A + (size_t)(m0 + r) * lda + kt + c8);
        }
#pragma unroll
        for (int i = 0; i < BN / 64; i++) {           // B: BNx32 u16
            int lin = i * 256 + t;
            int r = lin >> 2, c8 = (lin & 3) << 3;
            *reinterpret_cast<bf16x8*>(&Bs[r * LDT + c8]) =
                *reinterpret_cast<const bf16x8*>(Bt + (size_t)(n0 + r) * K + kt + c8);
        }
        __syncthreads();
        bf16x8 af[4], bfv[NI];
#pragma unroll
        for (int mi = 0; mi < 4; mi++)
            af[mi] = *reinterpret_cast<const bf16x8*>(&As[(wr * 64 + mi * 16 + l15) * LDT + lhi * 8]);
#pragma unroll
        for (int ni = 0; ni < NI; ni++)
            bfv[ni] = *reinterpret_cast<const bf16x8*>(&Bs[(wc * (BN / 2) + ni * 16 + l15) * LDT + lhi * 8]);
#pragma unroll
        for (int mi = 0; mi < 4; mi++)
#pragma unroll
            for (int ni = 0; ni < NI; ni++)
                acc[mi][ni] = __builtin_amdgcn_mfma_f32_16x16x32_bf16(af[mi], bfv[ni], acc[mi][ni], 0, 0, 0);
        __syncthreads();
    }

    float bb[NI];
#pragma unroll
    for (int ni = 0; ni < NI; ni++) bb[ni] = bias[n0 + wc * (BN / 2) + ni * 16 + l15];

    if (ROPE == 0) {
#pragma unroll
        for (int mi = 0; mi < 4; mi++) {
            int row = m0 + wr * 64 + mi * 16 + lhi * 4;
#pragma unroll
            for (int ni = 0; ni < NI; ni++) {
                int col = n0 + wc * (BN / 2) + ni * 16 + l15;
#pragma unroll
                for (int r = 0; r < 4; r++) {
                    float v = acc[mi][ni][r] + bb[ni];
                    if (ACT == 1) v = 0.5f * v * (1.0f + erff(v * 0.70710678118654752f));
                    C[(size_t)(row + r) * N + col] = f2bf(v);
                }
            }
        }
    } else {
#pragma unroll
        for (int ni = 0; ni < NI; ni++) {
            int colb = n0 + wc * (BN / 2) + ni * 16;
            int region = colb >> 9;                    // 0=q,1=k,2=v (block-uniform)
            int col = colb + l15;
            int d = col & 63;
            int head = (col >> 6) & 7;
#pragma unroll
            for (int mi = 0; mi < 4; mi++) {
#pragma unroll
                for (int r = 0; r < 4; r++) {
                    int row = m0 + wr * 64 + mi * 16 + lhi * 4 + r;
                    int sp = row & (S_ - 1);
                    int bidx = row >> 11;
                    float v = acc[mi][ni][r] + bb[ni];
                    if (region == 2) {
                        vd[(size_t)row * 512 + (col - 1024)] = f2bf(v);
                    } else {
                        float px = __shfl_xor(v, 1);
                        int f = d & 30;
                        float cs = rc[sp * 32 + f], sn = rs[sp * 32 + f];
                        float ov = (l15 & 1) ? fmaf(px, sn, v * cs)
                                             : fmaf(v, cs, -(px * sn));
                        if (region == 0) ov *= SCALE_;
                        u16* dst = (region == 0) ? qd : kd;
                        dst[((size_t)(bidx * 8 + head) * S_ + sp) * 64 + d] = f2bf(ov);
                    }
                }
            }
        }
    }
}

// ---------------------------------------------------------------- V transpose: bf16 [row][512] -> bf16 [b,h,d,s]
__global__ __launch_bounds__(256)
void vtrans_kernel(const u16* __restrict__ vin, u16* __restrict__ vout)
{
    __shared__ u16 tile[64][72];
    const int bh = blockIdx.y, b = bh >> 3, hh = bh & 7;
    const int s0 = blockIdx.x * 64;
    const int t = threadIdx.x;
#pragma unroll
    for (int i = 0; i < 4; i++) {
        int lin = i * 256 + t;
        int r = lin >> 4, c4 = (lin & 15) << 2;
        *reinterpret_cast<uint2*>(&tile[r][c4]) =
            *reinterpret_cast<const uint2*>(vin + (size_t)(b * S_ + s0 + r) * 512 + hh * 64 + c4);
    }
    __syncthreads();
#pragma unroll
    for (int i = 0; i < 4; i++) {
        int lin = i * 256 + t;
        int d = lin >> 4, c4 = (lin & 15) << 2;
        uint2 pk;
        pk.x = (u32)tile[c4 + 0][d] | ((u32)tile[c4 + 1][d] << 16);
        pk.y = (u32)tile[c4 + 2][d] | ((u32)tile[c4 + 3][d] << 16);
        *reinterpret_cast<uint2*>(vout + ((size_t)bh * 64 + d) * S_ + s0 + c4) = pk;
    }
}

// ---------------------------------------------------------------- flash attention, swapped-QK, 1 wave per 32 Q rows
// q pre-scaled by 1/sqrt(64).  S^T = mfma(K,Q): lane holds P[k=ni*16+lhi*4+r][q=mi*16+l15]
// -> softmax in-register (+2 shfl), P feeds 16x16x16 PV directly as B-frag, O^T accumulated.
__global__ __launch_bounds__(64)
void attn_kernel(const u16* __restrict__ qb, const u16* __restrict__ kb,
                 const u16* __restrict__ vt, const int* __restrict__ vid,
                 const float* __restrict__ maskp,
                 const float* __restrict__ usame, const float* __restrict__ ucross,
                 u16* __restrict__ o)
{
    const int bh = blockIdx.y;
    const int b = bh >> 3, hh = bh & 7;
    const int q0 = blockIdx.x * 32;
    const int lane = threadIdx.x;
    const int l15 = lane & 15, lhi = lane >> 4;
    const u16* qp = qb + (size_t)bh * S_ * 64;
    const u16* kp = kb + (size_t)bh * S_ * 64;
    const u16* vp = vt + (size_t)bh * 64 * S_;
    const float us = usame[hh], uc = ucross[hh], df = us - uc;

    bf16x8 qfr[2][2];
#pragma unroll
    for (int mi = 0; mi < 2; mi++)
#pragma unroll
        for (int kk = 0; kk < 2; kk++)
            qfr[mi][kk] = *reinterpret_cast<const bf16x8*>(
                qp + (size_t)(q0 + mi * 16 + l15) * 64 + kk * 32 + lhi * 8);

    const int vq[2] = { vid[b * S_ + q0 + l15], vid[b * S_ + q0 + 16 + l15] };

    float mrow[2] = { -1e30f, -1e30f }, lrow[2] = { 0.f, 0.f };
    f32x4 oT[4][2];
#pragma unroll
    for (int nd = 0; nd < 4; nd++)
#pragma unroll
        for (int mi = 0; mi < 2; mi++)
#pragma unroll
            for (int r = 0; r < 4; r++) oT[nd][mi][r] = 0.f;

    for (int kv0 = 0; kv0 < S_; kv0 += 32) {
        bf16x8 kfr[2][2];
#pragma unroll
        for (int ni = 0; ni < 2; ni++)
#pragma unroll
            for (int kk = 0; kk < 2; kk++)
                kfr[ni][kk] = *reinterpret_cast<const bf16x8*>(
                    kp + (size_t)(kv0 + ni * 16 + l15) * 64 + kk * 32 + lhi * 8);

        f32x4 sacc[2][2];                  // [ni][mi], S^T fragments
#pragma unroll
        for (int ni = 0; ni < 2; ni++)
#pragma unroll
            for (int mi = 0; mi < 2; mi++) {
#pragma unroll
                for (int r = 0; r < 4; r++) sacc[ni][mi][r] = 0.f;
                sacc[ni][mi] = __builtin_amdgcn_mfma_f32_16x16x32_bf16(kfr[ni][0], qfr[mi][0], sacc[ni][mi], 0, 0, 0);
                sacc[ni][mi] = __builtin_amdgcn_mfma_f32_16x16x32_bf16(kfr[ni][1], qfr[mi][1], sacc[ni][mi], 0, 0, 0);
            }

        i32x4 vk[2]; f32x4 mk[2];
#pragma unroll
        for (int ni = 0; ni < 2; ni++) {
            vk[ni] = *reinterpret_cast<const i32x4*>(vid + b * S_ + kv0 + ni * 16 + lhi * 4);
            mk[ni] = *reinterpret_cast<const f32x4*>(maskp + b * S_ + kv0 + ni * 16 + lhi * 4);
        }
        float kb_c[2][4], kb_s[2][4];
#pragma unroll
        for (int ni = 0; ni < 2; ni++)
#pragma unroll
            for (int r = 0; r < 4; r++) {
                float base = fmaf(1.0f - mk[ni][r], -1e9f, uc);
                kb_c[ni][r] = base;
                kb_s[ni][r] = base + df;
            }
#pragma unroll
        for (int mi = 0; mi < 2; mi++)
#pragma unroll
            for (int ni = 0; ni < 2; ni++)
#pragma unroll
                for (int r = 0; r < 4; r++)
                    sacc[ni][mi][r] += (vk[ni][r] == vq[mi]) ? kb_s[ni][r] : kb_c[ni][r];

        // softmax + P pack (per mi: 16 q-rows, lane-local stats)
        u32 pw[2][2][2];                    // [mi][ni][half]
#pragma unroll
        for (int mi = 0; mi < 2; mi++) {
            float pm = fmaxf(fmaxf(fmaxf(sacc[0][mi][0], sacc[0][mi][1]),
                                   fmaxf(sacc[0][mi][2], sacc[0][mi][3])),
                             fmaxf(fmaxf(sacc[1][mi][0], sacc[1][mi][1]),
                                   fmaxf(sacc[1][mi][2], sacc[1][mi][3])));
            pm = fmaxf(pm, __shfl_xor(pm, 16));
            pm = fmaxf(pm, __shfl_xor(pm, 32));
            float mnew = fmaxf(mrow[mi], pm);
            float alpha = __expf(mrow[mi] - mnew);
            mrow[mi] = mnew;
            float ps[2][4];
#pragma unroll
            for (int ni = 0; ni < 2; ni++)
#pragma unroll
                for (int r = 0; r < 4; r++)
                    ps[ni][r] = __expf(sacc[ni][mi][r] - mnew);
            float rsum = ((ps[0][0] + ps[0][1]) + (ps[0][2] + ps[0][3]))
                       + ((ps[1][0] + ps[1][1]) + (ps[1][2] + ps[1][3]));
            rsum += __shfl_xor(rsum, 16);
            rsum += __shfl_xor(rsum, 32);
            lrow[mi] = lrow[mi] * alpha + rsum;
#pragma unroll
            for (int nd = 0; nd < 4; nd++)
#pragma unroll
                for (int r = 0; r < 4; r++) oT[nd][mi][r] *= alpha;
#pragma unroll
            for (int ni = 0; ni < 2; ni++) {
                pw[mi][ni][0] = cvt_pk_bf16(ps[ni][0], ps[ni][1]);
                pw[mi][ni][1] = cvt_pk_bf16(ps[ni][2], ps[ni][3]);
            }
        }

        bf16x4 vfr[4][2];
#pragma unroll
        for (int nd = 0; nd < 4; nd++)
#pragma unroll
            for (int ni = 0; ni < 2; ni++)
                vfr[nd][ni] = *reinterpret_cast<const bf16x4*>(
                    vp + (size_t)(nd * 16 + l15) * S_ + kv0 + ni * 16 + lhi * 4);

#pragma unroll
        for (int mi = 0; mi < 2; mi++) {
            bf16x4 pb[2];
#pragma unroll
            for (int ni = 0; ni < 2; ni++) {
                union { u32 u[2]; bf16x4 h; } uu;
                uu.u[0] = pw[mi][ni][0];
                uu.u[1] = pw[mi][ni][1];
                pb[ni] = uu.h;
            }
#pragma unroll
            for (int nd = 0; nd < 4; nd++)
#pragma unroll
                for (int ni = 0; ni < 2; ni++)
                    oT[nd][mi] = __builtin_amdgcn_mfma_f32_16x16x16bf16_1k(vfr[nd][ni], pb[ni], oT[nd][mi], 0, 0, 0);
        }
    }

#pragma unroll
    for (int mi = 0; mi < 2; mi++) {
        float inv = 1.0f / lrow[mi];
        size_t rowb = (size_t)(b * S_ + q0 + mi * 16 + l15) * D_;
#pragma unroll
        for (int nd = 0; nd < 4; nd++) {
            uint2 st;
            st.x = cvt_pk_bf16(oT[nd][mi][0] * inv, oT[nd][mi][1] * inv);
            st.y = cvt_pk_bf16(oT[nd][mi][2] * inv, oT[nd][mi][3] * inv);
            *reinterpret_cast<uint2*>(o + rowb + hh * 64 + nd * 16 + lhi * 4) = st;
        }
    }
}

// ---------------------------------------------------------------- LayerNorm: hb = LN(hb + t)*g + be  (bf16 in/out)
__global__ __launch_bounds__(64)
void ln_kernel(u16* hb, const u16* __restrict__ tb,
               const float* __restrict__ g, const float* __restrict__ be)
{
    const int row = blockIdx.x;
    const int lane = threadIdx.x;
    u16* hp = hb + (size_t)row * D_ + lane * 8;
    const u16* tp = tb + (size_t)row * D_ + lane * 8;
    bf16x8 a = *reinterpret_cast<const bf16x8*>(hp);
    bf16x8 c = *reinterpret_cast<const bf16x8*>(tp);
    float x[8];
    float s = 0.f, s2 = 0.f;
#pragma unroll
    for (int j = 0; j < 8; j++) {
        x[j] = bf2f((u16)a[j]) + bf2f((u16)c[j]);
        s += x[j]; s2 += x[j] * x[j];
    }
#pragma unroll
    for (int m = 1; m <= 32; m <<= 1) { s += __shfl_xor(s, m); s2 += __shfl_xor(s2, m); }
    float mean = s * (1.0f / 512.0f);
    float var = s2 * (1.0f / 512.0f) - mean * mean;
    float rstd = rsqrtf(var + 1e-5f);
    const float* gp = g + lane * 8;
    const float* bp = be + lane * 8;
    bf16x8 ov;
#pragma unroll
    for (int j = 0; j < 8; j++)
        ov[j] = (short)f2bf((x[j] - mean) * rstd * gp[j] + bp[j]);
    *reinterpret_cast<bf16x8*>(hp) = ov;
}

// ---------------------------------------------------------------- head: out(f32) = hb(bf16) @ Wh + bh  (N=32)
__global__ __launch_bounds__(256)
void head_kernel(const u16* __restrict__ hb, const float* __restrict__ Wh,
                 const float* __restrict__ bhv, float* __restrict__ out)
{
    const int t = threadIdx.x;
    const int p = t & 31, sub = t >> 5;
    const int row = blockIdx.x * 8 + sub;
    const u16* hp = hb + (size_t)row * D_;
    float acc = 0.f;
#pragma unroll 4
    for (int k0 = 0; k0 < D_; k0 += 8) {
        bf16x8 hv = *reinterpret_cast<const bf16x8*>(hp + k0);
#pragma unroll
        for (int j = 0; j < 8; j++)
            acc = fmaf(bf2f((u16)hv[j]), Wh[(size_t)(k0 + j) * 32 + p], acc);
    }
    out[(size_t)row * 32 + p] = acc + bhv[p];
}

// ---------------------------------------------------------------- launch
extern "C" void kernel_launch(void* const* d_in, const int* in_sizes, int n_in,
                              void* d_out, int out_size, void* d_ws, size_t ws_size,
                              hipStream_t stream)
{
    (void)in_sizes; (void)n_in; (void)out_size; (void)ws_size;
    const float* x     = (const float*)d_in[0];
    const int*   vid   = (const int*)d_in[1];
    const float* maskp = (const float*)d_in[2];
    const float* Wpe   = (const float*)d_in[3];
    const float* bpe   = (const float*)d_in[4];
    const float* Wq    = (const float*)d_in[5];
    const float* bq    = (const float*)d_in[6];
    const float* Wk    = (const float*)d_in[7];
    const float* bk    = (const float*)d_in[8];
    const float* Wv    = (const float*)d_in[9];
    const float* bv    = (const float*)d_in[10];
    const float* Wo    = (const float*)d_in[11];
    const float* bo    = (const float*)d_in[12];
    const float* usame = (const float*)d_in[13];
    const float* ucros = (const float*)d_in[14];
    const float* g1    = (const float*)d_in[15];
    const float* be1   = (const float*)d_in[16];
    const float* W1    = (const float*)d_in[17];
    const float* b1f   = (const float*)d_in[18];
    const float* W2    = (const float*)d_in[19];
    const float* b2f   = (const float*)d_in[20];
    const float* g2    = (const float*)d_in[21];
    const float* be2   = (const float*)d_in[22];
    const float* Whd   = (const float*)d_in[23];
    const float* bhd   = (const float*)d_in[24];

    constexpr size_t MB = 1024ull * 1024ull;
    char* ws = (char*)d_ws;
    u16*   hb   = (u16*)(ws + 0);          // 8 MB
    u16*   qbb  = (u16*)(ws + 8 * MB);     // 8 MB [b,h,s,64], pre-scaled
    u16*   kbb  = (u16*)(ws + 16 * MB);    // 8 MB [b,h,s,64]
    u16*   vf16 = (u16*)(ws + 24 * MB);    // 8 MB [row][512]
    u16*   vtb  = (u16*)(ws + 32 * MB);    // 8 MB [b,h,d,s]
    u16*   ob   = (u16*)(ws + 40 * MB);    // 8 MB
    u16*   tb   = (u16*)(ws + 48 * MB);    // 8 MB
    u16*   fb   = (u16*)(ws + 56 * MB);    // 32 MB
    u16*   xb   = (u16*)(ws + 88 * MB);    // 0.5 MB
    float* rc   = (float*)(ws + 89 * MB);
    float* rs   = (float*)(ws + 89 * MB + 262144);
    float* bqkv = (float*)(ws + 90 * MB);
    u16*   wpe_t = (u16*)(ws + 91 * MB);
    u16*   wbase = (u16*)(ws + 92 * MB);   // per layer 3145728 u16 (6MB)

    auto qkvt = [&](int l) { return wbase + (size_t)l * 3145728; };
    auto wot  = [&](int l) { return qkvt(l) + 786432; };
    auto w1t  = [&](int l) { return wot(l) + 262144; };
    auto w2t  = [&](int l) { return w1t(l) + 1048576; };

    // prep
    f2b_kernel<<<256, 256, 0, stream>>>(x, xb, 65536);
    wtrans_kernel<<<dim3(16, 1), 256, 0, stream>>>(Wpe, wpe_t, 32, 512);
    for (int l = 0; l < L_; l++) {
        wtrans_kernel<<<dim3(16, 16), 256, 0, stream>>>(Wq + (size_t)l * 262144, qkvt(l), 512, 512);
        wtrans_kernel<<<dim3(16, 16), 256, 0, stream>>>(Wk + (size_t)l * 262144, qkvt(l) + 262144, 512, 512);
        wtrans_kernel<<<dim3(16, 16), 256, 0, stream>>>(Wv + (size_t)l * 262144, qkvt(l) + 524288, 512, 512);
        wtrans_kernel<<<dim3(16, 16), 256, 0, stream>>>(Wo + (size_t)l * 262144, wot(l), 512, 512);
        wtrans_kernel<<<dim3(64, 16), 256, 0, stream>>>(W1 + (size_t)l * 1048576, w1t(l), 512, 2048);
        wtrans_kernel<<<dim3(16, 64), 256, 0, stream>>>(W2 + (size_t)l * 1048576, w2t(l), 2048, 512);
    }
    bcat_kernel<<<12, 256, 0, stream>>>(bq, bk, bv, bqkv);
    rope_table_kernel<<<256, 256, 0, stream>>>(rc, rs);

    // embed: hb = bf16(x @ W_pe + b_pe)
    gemm_kernel<0, 64, 0><<<dim3(8, 64), 256, 0, stream>>>(
        xb, wpe_t, bpe, hb, BS_, 512, 32, 32,
        (u16*)nullptr, (u16*)nullptr, (u16*)nullptr, (const float*)nullptr, (const float*)nullptr);

    for (int l = 0; l < L_; l++) {
        // fused QKV + rope + relayout
        gemm_kernel<0, 128, 1><<<dim3(12, 64), 256, 0, stream>>>(
            hb, qkvt(l), bqkv + l * 1536, (u16*)nullptr, BS_, 1536, 512, 512,
            qbb, kbb, vf16, rc, rs);
        vtrans_kernel<<<dim3(32, 32), 256, 0, stream>>>(vf16, vtb);
        attn_kernel<<<dim3(64, 32), 64, 0, stream>>>(qbb, kbb, vtb, vid, maskp,
                                                     usame + l * H_, ucros + l * H_, ob);
        gemm_kernel<0, 64, 0><<<dim3(8, 64), 256, 0, stream>>>(
            ob, wot(l), bo + l * 512, tb, BS_, 512, 512, 512,
            (u16*)nullptr, (u16*)nullptr, (u16*)nullptr, (const float*)nullptr, (const float*)nullptr);
        ln_kernel<<<8192, 64, 0, stream>>>(hb, tb, g1 + l * 512, be1 + l * 512);
        gemm_kernel<1, 128, 0><<<dim3(16, 64), 256, 0, stream>>>(
            hb, w1t(l), b1f + l * 2048, fb, BS_, 2048, 512, 512,
            (u16*)nullptr, (u16*)nullptr, (u16*)nullptr, (const float*)nullptr, (const float*)nullptr);
        gemm_kernel<0, 64, 0><<<dim3(8, 64), 256, 0, stream>>>(
            fb, w2t(l), b2f + l * 512, tb, BS_, 512, 2048, 2048,
            (u16*)nullptr, (u16*)nullptr, (u16*)nullptr, (const float*)nullptr, (const float*)nullptr);
        ln_kernel<<<8192, 64, 0, stream>>>(hb, tb, g2 + l * 512, be2 + l * 512);
    }
    head_kernel<<<1024, 256, 0, stream>>>(hb, Whd, bhd, (float*)d_out);
}

// Round 4
// 764.504 us; speedup vs baseline: 1.2700x; 1.0254x over previous
//
#include <hip/hip_runtime.h>

typedef unsigned short u16;
typedef unsigned int   u32;
typedef __attribute__((ext_vector_type(8))) short bf16x8;
typedef __attribute__((ext_vector_type(4))) short bf16x4;
typedef __attribute__((ext_vector_type(4))) float f32x4;
typedef __attribute__((ext_vector_type(4))) int   i32x4;

constexpr int B_ = 4, S_ = 2048, D_ = 512, H_ = 8, L_ = 2, DFF_ = 2048;
constexpr int BS_ = B_ * S_;            // 8192 token rows
constexpr float SCALE_ = 0.125f;        // 1/sqrt(64)

__device__ __forceinline__ u16 f2bf(float f) {
    u32 u = __float_as_uint(f);
    u += 0x7fffu + ((u >> 16) & 1u);    // RTNE
    return (u16)(u >> 16);
}
__device__ __forceinline__ float bf2f(u16 u) {
    return __uint_as_float(((u32)u) << 16);
}
__device__ __forceinline__ u32 cvt_pk_bf16(float lo, float hi) {
    u32 d;
    asm volatile("v_cvt_pk_bf16_f32 %0, %1, %2" : "=v"(d) : "v"(lo), "v"(hi));
    return d;
}

// ---------------------------------------------------------------- weight transpose: Wt[n*K+k] = bf16(W[k*N+n])
__global__ __launch_bounds__(256)
void wtrans_kernel(const float* __restrict__ W, u16* __restrict__ Wt, int K, int N)
{
    __shared__ float tile[32][33];
    const int n0 = blockIdx.x * 32, k0 = blockIdx.y * 32;
    const int t = threadIdx.x;
#pragma unroll
    for (int i = 0; i < 4; i++) {
        int lin = i * 256 + t;
        int r = lin >> 5, c = lin & 31;
        tile[r][c] = W[(size_t)(k0 + r) * N + n0 + c];
    }
    __syncthreads();
#pragma unroll
    for (int i = 0; i < 4; i++) {
        int lin = i * 256 + t;
        int r = lin >> 5, c = lin & 31;
        Wt[(size_t)(n0 + r) * K + k0 + c] = f2bf(tile[c][r]);
    }
}

// ---------------------------------------------------------------- f32 -> bf16 bulk convert (for x)
__global__ __launch_bounds__(256)
void f2b_kernel(const float* __restrict__ in, u16* __restrict__ out, int n4)
{
    int i = blockIdx.x * 256 + threadIdx.x;
    if (i < n4) {
        float4 f = *reinterpret_cast<const float4*>(in + (size_t)i * 4);
        uint2 pk;
        pk.x = (u32)f2bf(f.x) | ((u32)f2bf(f.y) << 16);
        pk.y = (u32)f2bf(f.z) | ((u32)f2bf(f.w) << 16);
        *reinterpret_cast<uint2*>(out + (size_t)i * 4) = pk;
    }
}

// ---------------------------------------------------------------- bias concat for fused QKV
__global__ __launch_bounds__(256)
void bcat_kernel(const float* __restrict__ bq, const float* __restrict__ bk,
                 const float* __restrict__ bv, float* __restrict__ o)
{
    int idx = blockIdx.x * 256 + threadIdx.x;
    if (idx < L_ * 1536) {
        int l = idx / 1536, i = idx % 1536;
        float v = (i < 512) ? bq[l * 512 + i]
                : (i < 1024) ? bk[l * 512 + i - 512]
                             : bv[l * 512 + i - 1024];
        o[idx] = v;
    }
}

// ---------------------------------------------------------------- rope tables (f32, [s][32] for cos/sin)
__global__ __launch_bounds__(256)
void rope_table_kernel(float* __restrict__ rc, float* __restrict__ rs)
{
    int idx = blockIdx.x * 256 + threadIdx.x;   // S_*32 = 65536
    int j = idx & 31, tpos = idx >> 5;
    float inv = __expf(-(float)j * 0.28782313662425572f);  // 10000^(-j/32)
    float ang = (float)tpos * inv;
    rc[idx] = cosf(ang);
    rs[idx] = sinf(ang);
}

// ---------------------------------------------------------------- GEMM: C(bf16) = A(bf16,MxK,lda) @ Bt^T(bf16,NxK) + bias
// ACT=1: exact GELU.  ROPE=1 (BN=128, N=1536): fused rope + [b,h,s,d] relayout for q/k, v passthrough.
template<int ACT, int BN, int ROPE>
__global__ __launch_bounds__(256)
void gemm_kernel(const u16* __restrict__ A, const u16* __restrict__ Bt,
                 const float* __restrict__ bias, u16* __restrict__ C,
                 int M, int N, int K, int lda,
                 u16* __restrict__ qd, u16* __restrict__ kd, u16* __restrict__ vd,
                 const float* __restrict__ rc, const float* __restrict__ rs)
{
    constexpr int LDT = 40;                // padded u16 row stride
    constexpr int NI = BN / 32;
    __shared__ u16 As[128 * LDT];
    __shared__ u16 Bs[BN * LDT];
    const int t = threadIdx.x;
    const int m0 = blockIdx.y * 128, n0 = blockIdx.x * BN;
    const int lane = t & 63, w = t >> 6;
    const int wr = w >> 1, wc = w & 1;
    const int l15 = lane & 15, lhi = lane >> 4;

    f32x4 acc[4][NI];
#pragma unroll
    for (int i = 0; i < 4; i++)
#pragma unroll
        for (int j = 0; j < NI; j++)
#pragma unroll
            for (int r = 0; r < 4; r++) acc[i][j][r] = 0.f;

    for (int kt = 0; kt < K; kt += 32) {
#pragma unroll
        for (int i = 0; i < 2; i++) {                 // A: 128x32 u16 = 512 chunks
            int lin = i * 256 + t;
            int r = lin >> 2, c8 = (lin & 3) << 3;
            *reinterpret_cast<bf16x8*>(&As[r * LDT + c8]) =
                *reinterpret_cast<const bf16x8*>(A + (size_t)(m0 + r) * lda + kt + c8);
        }
#pragma unroll
        for (int i = 0; i < BN / 64; i++) {           // B: BNx32 u16
            int lin = i * 256 + t;
            int r = lin >> 2, c8 = (lin & 3) << 3;
            *reinterpret_cast<bf16x8*>(&Bs[r * LDT + c8]) =
                *reinterpret_cast<const bf16x8*>(Bt + (size_t)(n0 + r) * K + kt + c8);
        }
        __syncthreads();
        bf16x8 af[4], bfv[NI];
#pragma unroll
        for (int mi = 0; mi < 4; mi++)
            af[mi] = *reinterpret_cast<const bf16x8*>(&As[(wr * 64 + mi * 16 + l15) * LDT + lhi * 8]);
#pragma unroll
        for (int ni = 0; ni < NI; ni++)
            bfv[ni] = *reinterpret_cast<const bf16x8*>(&Bs[(wc * (BN / 2) + ni * 16 + l15) * LDT + lhi * 8]);
#pragma unroll
        for (int mi = 0; mi < 4; mi++)
#pragma unroll
            for (int ni = 0; ni < NI; ni++)
                acc[mi][ni] = __builtin_amdgcn_mfma_f32_16x16x32_bf16(af[mi], bfv[ni], acc[mi][ni], 0, 0, 0);
        __syncthreads();
    }

    float bb[NI];
#pragma unroll
    for (int ni = 0; ni < NI; ni++) bb[ni] = bias[n0 + wc * (BN / 2) + ni * 16 + l15];

    if (ROPE == 0) {
#pragma unroll
        for (int mi = 0; mi < 4; mi++) {
            int row = m0 + wr * 64 + mi * 16 + lhi * 4;
#pragma unroll
            for (int ni = 0; ni < NI; ni++) {
                int col = n0 + wc * (BN / 2) + ni * 16 + l15;
#pragma unroll
                for (int r = 0; r < 4; r++) {
                    float v = acc[mi][ni][r] + bb[ni];
                    if (ACT == 1) v = 0.5f * v * (1.0f + erff(v * 0.70710678118654752f));
                    C[(size_t)(row + r) * N + col] = f2bf(v);
                }
            }
        }
    } else {
#pragma unroll
        for (int ni = 0; ni < NI; ni++) {
            int colb = n0 + wc * (BN / 2) + ni * 16;
            int region = colb >> 9;                    // 0=q,1=k,2=v (block-uniform)
            int col = colb + l15;
            int d = col & 63;
            int head = (col >> 6) & 7;
#pragma unroll
            for (int mi = 0; mi < 4; mi++) {
#pragma unroll
                for (int r = 0; r < 4; r++) {
                    int row = m0 + wr * 64 + mi * 16 + lhi * 4 + r;
                    int sp = row & (S_ - 1);
                    int bidx = row >> 11;
                    float v = acc[mi][ni][r] + bb[ni];
                    if (region == 2) {
                        vd[(size_t)row * 512 + (col - 1024)] = f2bf(v);
                    } else {
                        float px = __shfl_xor(v, 1);
                        int f = d & 30;
                        float cs = rc[sp * 32 + f], sn = rs[sp * 32 + f];
                        float ov = (l15 & 1) ? fmaf(px, sn, v * cs)
                                             : fmaf(v, cs, -(px * sn));
                        if (region == 0) ov *= SCALE_;
                        u16* dst = (region == 0) ? qd : kd;
                        dst[((size_t)(bidx * 8 + head) * S_ + sp) * 64 + d] = f2bf(ov);
                    }
                }
            }
        }
    }
}

// ---------------------------------------------------------------- V transpose: bf16 [row][512] -> bf16 [b,h,d,s]
__global__ __launch_bounds__(256)
void vtrans_kernel(const u16* __restrict__ vin, u16* __restrict__ vout)
{
    __shared__ u16 tile[64][72];
    const int bh = blockIdx.y, b = bh >> 3, hh = bh & 7;
    const int s0 = blockIdx.x * 64;
    const int t = threadIdx.x;
#pragma unroll
    for (int i = 0; i < 4; i++) {
        int lin = i * 256 + t;
        int r = lin >> 4, c4 = (lin & 15) << 2;
        *reinterpret_cast<uint2*>(&tile[r][c4]) =
            *reinterpret_cast<const uint2*>(vin + (size_t)(b * S_ + s0 + r) * 512 + hh * 64 + c4);
    }
    __syncthreads();
#pragma unroll
    for (int i = 0; i < 4; i++) {
        int lin = i * 256 + t;
        int d = lin >> 4, c4 = (lin & 15) << 2;
        uint2 pk;
        pk.x = (u32)tile[c4 + 0][d] | ((u32)tile[c4 + 1][d] << 16);
        pk.y = (u32)tile[c4 + 2][d] | ((u32)tile[c4 + 3][d] << 16);
        *reinterpret_cast<uint2*>(vout + ((size_t)bh * 64 + d) * S_ + s0 + c4) = pk;
    }
}

// ---------------------------------------------------------------- flash attention, swapped-QK, 1 wave per 32 Q rows
// KVBLK=64, K double-buffered, V issued a phase early, vid/mask in LDS,
// defer-max (THR=8), XCD-pinned block swizzle (4 heads per XCD -> 2MB L2 set).
__global__ __launch_bounds__(64)
void attn_kernel(const u16* __restrict__ qbp, const u16* __restrict__ kbp,
                 const u16* __restrict__ vt, const int* __restrict__ vid,
                 const float* __restrict__ maskp,
                 const float* __restrict__ usame, const float* __restrict__ ucross,
                 u16* __restrict__ o)
{
    __shared__ int   vids[S_];
    __shared__ float madds[S_];
    const int bidx = blockIdx.x;
    const int xcd = bidx & 7;
    const int jj = bidx >> 3;               // 0..255
    const int bh = xcd * 4 + (jj >> 6);     // 4 heads pinned per XCD
    const int q0 = (jj & 63) * 32;
    const int b = bh >> 3, hh = bh & 7;
    const int lane = threadIdx.x;
    const int l15 = lane & 15, lhi = lane >> 4;
    const u16* qp = qbp + (size_t)bh * S_ * 64;
    const u16* kp = kbp + (size_t)bh * S_ * 64;
    const u16* vp = vt + (size_t)bh * 64 * S_;
    const float us = usame[hh], uc = ucross[hh];

    // stage vid + mask-add for this batch into LDS (vectorized, once)
    for (int i = lane; i < S_ / 4; i += 64) {
        i32x4 vv = reinterpret_cast<const i32x4*>(vid + (size_t)b * S_)[i];
        f32x4 mm = reinterpret_cast<const f32x4*>(maskp + (size_t)b * S_)[i];
        f32x4 md;
#pragma unroll
        for (int r = 0; r < 4; r++) md[r] = (1.0f - mm[r]) * -1e9f;
        reinterpret_cast<i32x4*>(vids)[i] = vv;
        reinterpret_cast<f32x4*>(madds)[i] = md;
    }
    __syncthreads();

    bf16x8 qfr[2][2];
#pragma unroll
    for (int mi = 0; mi < 2; mi++)
#pragma unroll
        for (int kk = 0; kk < 2; kk++)
            qfr[mi][kk] = *reinterpret_cast<const bf16x8*>(
                qp + (size_t)(q0 + mi * 16 + l15) * 64 + kk * 32 + lhi * 8);

    const int vq[2] = { vids[q0 + l15], vids[q0 + 16 + l15] };

    float mrow[2] = { -1e30f, -1e30f }, lrow[2] = { 0.f, 0.f };
    f32x4 oT[4][2];
#pragma unroll
    for (int nd = 0; nd < 4; nd++)
#pragma unroll
        for (int mi = 0; mi < 2; mi++)
#pragma unroll
            for (int r = 0; r < 4; r++) oT[nd][mi][r] = 0.f;

    bf16x8 kA[4][2], kB[4][2];
    bf16x4 vbuf[4][4];
    f32x4 sacc[4][2];                        // [ni][mi] S^T fragments

    auto load_k = [&](int kv0, bf16x8 (&kf)[4][2]) {
#pragma unroll
        for (int ni = 0; ni < 4; ni++)
#pragma unroll
            for (int kk = 0; kk < 2; kk++)
                kf[ni][kk] = *reinterpret_cast<const bf16x8*>(
                    kp + (size_t)(kv0 + ni * 16 + l15) * 64 + kk * 32 + lhi * 8);
    };
    auto load_v = [&](int kv0) {
#pragma unroll
        for (int nd = 0; nd < 4; nd++)
#pragma unroll
            for (int ni = 0; ni < 4; ni++)
                vbuf[nd][ni] = *reinterpret_cast<const bf16x4*>(
                    vp + (size_t)(nd * 16 + l15) * S_ + kv0 + ni * 16 + lhi * 4);
    };
    auto qk = [&](bf16x8 (&kf)[4][2]) {
#pragma unroll
        for (int ni = 0; ni < 4; ni++)
#pragma unroll
            for (int mi = 0; mi < 2; mi++) {
#pragma unroll
                for (int r = 0; r < 4; r++) sacc[ni][mi][r] = 0.f;
                sacc[ni][mi] = __builtin_amdgcn_mfma_f32_16x16x32_bf16(kf[ni][0], qfr[mi][0], sacc[ni][mi], 0, 0, 0);
                sacc[ni][mi] = __builtin_amdgcn_mfma_f32_16x16x32_bf16(kf[ni][1], qfr[mi][1], sacc[ni][mi], 0, 0, 0);
            }
    };
    auto soft_pv = [&](int kv0) {
        i32x4 vkq[4]; f32x4 mdq[4];
#pragma unroll
        for (int ni = 0; ni < 4; ni++) {
            vkq[ni] = *reinterpret_cast<const i32x4*>(&vids[kv0 + ni * 16 + lhi * 4]);
            mdq[ni] = *reinterpret_cast<const f32x4*>(&madds[kv0 + ni * 16 + lhi * 4]);
        }
#pragma unroll
        for (int mi = 0; mi < 2; mi++)
#pragma unroll
            for (int ni = 0; ni < 4; ni++)
#pragma unroll
                for (int r = 0; r < 4; r++)
                    sacc[ni][mi][r] += mdq[ni][r] + ((vkq[ni][r] == vq[mi]) ? us : uc);
#pragma unroll
        for (int mi = 0; mi < 2; mi++) {
            float pm = sacc[0][mi][0];
#pragma unroll
            for (int ni = 0; ni < 4; ni++)
#pragma unroll
                for (int r = 0; r < 4; r++)
                    if (ni || r) pm = fmaxf(pm, sacc[ni][mi][r]);
            pm = fmaxf(pm, __shfl_xor(pm, 16));
            pm = fmaxf(pm, __shfl_xor(pm, 32));
            if (!__all(pm <= mrow[mi] + 8.f)) {       // defer-max: rescale only on growth
                float mnew = fmaxf(mrow[mi], pm);
                float alpha = __expf(mrow[mi] - mnew);
                mrow[mi] = mnew;
                lrow[mi] *= alpha;
#pragma unroll
                for (int nd = 0; nd < 4; nd++)
#pragma unroll
                    for (int r = 0; r < 4; r++) oT[nd][mi][r] *= alpha;
            }
            float ps[4][4];
#pragma unroll
            for (int ni = 0; ni < 4; ni++)
#pragma unroll
                for (int r = 0; r < 4; r++)
                    ps[ni][r] = __expf(sacc[ni][mi][r] - mrow[mi]);
            float rsum = ((ps[0][0] + ps[0][1]) + (ps[0][2] + ps[0][3]))
                       + ((ps[1][0] + ps[1][1]) + (ps[1][2] + ps[1][3]))
                       + ((ps[2][0] + ps[2][1]) + (ps[2][2] + ps[2][3]))
                       + ((ps[3][0] + ps[3][1]) + (ps[3][2] + ps[3][3]));
            rsum += __shfl_xor(rsum, 16);
            rsum += __shfl_xor(rsum, 32);
            lrow[mi] += rsum;
            bf16x4 pb[4];
#pragma unroll
            for (int ni = 0; ni < 4; ni++) {
                union { u32 u[2]; bf16x4 h; } uu;
                uu.u[0] = cvt_pk_bf16(ps[ni][0], ps[ni][1]);
                uu.u[1] = cvt_pk_bf16(ps[ni][2], ps[ni][3]);
                pb[ni] = uu.h;
            }
#pragma unroll
            for (int nd = 0; nd < 4; nd++)
#pragma unroll
                for (int ni = 0; ni < 4; ni++)
                    oT[nd][mi] = __builtin_amdgcn_mfma_f32_16x16x16bf16_1k(vbuf[nd][ni], pb[ni], oT[nd][mi], 0, 0, 0);
        }
    };

    load_k(0, kA);
    for (int kv0 = 0; kv0 < S_; kv0 += 128) {
        load_v(kv0);                         // V for tile A (hides under QK+softmax A)
        load_k(kv0 + 64, kB);                // K for tile B
        qk(kA);
        soft_pv(kv0);
        load_v(kv0 + 64);                    // V for tile B
        if (kv0 + 128 < S_) load_k(kv0 + 128, kA);
        qk(kB);
        soft_pv(kv0 + 64);
    }

#pragma unroll
    for (int mi = 0; mi < 2; mi++) {
        float inv = 1.0f / lrow[mi];
        size_t rowb = (size_t)(b * S_ + q0 + mi * 16 + l15) * D_;
#pragma unroll
        for (int nd = 0; nd < 4; nd++) {
            uint2 st;
            st.x = cvt_pk_bf16(oT[nd][mi][0] * inv, oT[nd][mi][1] * inv);
            st.y = cvt_pk_bf16(oT[nd][mi][2] * inv, oT[nd][mi][3] * inv);
            *reinterpret_cast<uint2*>(o + rowb + hh * 64 + nd * 16 + lhi * 4) = st;
        }
    }
}

// ---------------------------------------------------------------- LayerNorm: hb = LN(hb + t)*g + be  (bf16 in/out)
__global__ __launch_bounds__(64)
void ln_kernel(u16* hb, const u16* __restrict__ tb,
               const float* __restrict__ g, const float* __restrict__ be)
{
    const int row = blockIdx.x;
    const int lane = threadIdx.x;
    u16* hp = hb + (size_t)row * D_ + lane * 8;
    const u16* tp = tb + (size_t)row * D_ + lane * 8;
    bf16x8 a = *reinterpret_cast<const bf16x8*>(hp);
    bf16x8 c = *reinterpret_cast<const bf16x8*>(tp);
    float x[8];
    float s = 0.f, s2 = 0.f;
#pragma unroll
    for (int j = 0; j < 8; j++) {
        x[j] = bf2f((u16)a[j]) + bf2f((u16)c[j]);
        s += x[j]; s2 += x[j] * x[j];
    }
#pragma unroll
    for (int m = 1; m <= 32; m <<= 1) { s += __shfl_xor(s, m); s2 += __shfl_xor(s2, m); }
    float mean = s * (1.0f / 512.0f);
    float var = s2 * (1.0f / 512.0f) - mean * mean;
    float rstd = rsqrtf(var + 1e-5f);
    const float* gp = g + lane * 8;
    const float* bp = be + lane * 8;
    bf16x8 ov;
#pragma unroll
    for (int j = 0; j < 8; j++)
        ov[j] = (short)f2bf((x[j] - mean) * rstd * gp[j] + bp[j]);
    *reinterpret_cast<bf16x8*>(hp) = ov;
}

// ---------------------------------------------------------------- head: out(f32) = hb(bf16) @ Wh + bh  (N=32)
__global__ __launch_bounds__(256)
void head_kernel(const u16* __restrict__ hb, const float* __restrict__ Wh,
                 const float* __restrict__ bhv, float* __restrict__ out)
{
    const int t = threadIdx.x;
    const int p = t & 31, sub = t >> 5;
    const int row = blockIdx.x * 8 + sub;
    const u16* hp = hb + (size_t)row * D_;
    float acc = 0.f;
#pragma unroll 4
    for (int k0 = 0; k0 < D_; k0 += 8) {
        bf16x8 hv = *reinterpret_cast<const bf16x8*>(hp + k0);
#pragma unroll
        for (int j = 0; j < 8; j++)
            acc = fmaf(bf2f((u16)hv[j]), Wh[(size_t)(k0 + j) * 32 + p], acc);
    }
    out[(size_t)row * 32 + p] = acc + bhv[p];
}

// ---------------------------------------------------------------- launch
extern "C" void kernel_launch(void* const* d_in, const int* in_sizes, int n_in,
                              void* d_out, int out_size, void* d_ws, size_t ws_size,
                              hipStream_t stream)
{
    (void)in_sizes; (void)n_in; (void)out_size; (void)ws_size;
    const float* x     = (const float*)d_in[0];
    const int*   vid   = (const int*)d_in[1];
    const float* maskp = (const float*)d_in[2];
    const float* Wpe   = (const float*)d_in[3];
    const float* bpe   = (const float*)d_in[4];
    const float* Wq    = (const float*)d_in[5];
    const float* bq    = (const float*)d_in[6];
    const float* Wk    = (const float*)d_in[7];
    const float* bk    = (const float*)d_in[8];
    const float* Wv    = (const float*)d_in[9];
    const float* bv    = (const float*)d_in[10];
    const float* Wo    = (const float*)d_in[11];
    const float* bo    = (const float*)d_in[12];
    const float* usame = (const float*)d_in[13];
    const float* ucros = (const float*)d_in[14];
    const float* g1    = (const float*)d_in[15];
    const float* be1   = (const float*)d_in[16];
    const float* W1    = (const float*)d_in[17];
    const float* b1f   = (const float*)d_in[18];
    const float* W2    = (const float*)d_in[19];
    const float* b2f   = (const float*)d_in[20];
    const float* g2    = (const float*)d_in[21];
    const float* be2   = (const float*)d_in[22];
    const float* Whd   = (const float*)d_in[23];
    const float* bhd   = (const float*)d_in[24];

    constexpr size_t MB = 1024ull * 1024ull;
    char* ws = (char*)d_ws;
    u16*   hb   = (u16*)(ws + 0);          // 8 MB
    u16*   qbb  = (u16*)(ws + 8 * MB);     // 8 MB [b,h,s,64], pre-scaled
    u16*   kbb  = (u16*)(ws + 16 * MB);    // 8 MB [b,h,s,64]
    u16*   vf16 = (u16*)(ws + 24 * MB);    // 8 MB [row][512]
    u16*   vtb  = (u16*)(ws + 32 * MB);    // 8 MB [b,h,d,s]
    u16*   ob   = (u16*)(ws + 40 * MB);    // 8 MB
    u16*   tb   = (u16*)(ws + 48 * MB);    // 8 MB
    u16*   fb   = (u16*)(ws + 56 * MB);    // 32 MB
    u16*   xb   = (u16*)(ws + 88 * MB);    // 0.5 MB
    float* rc   = (float*)(ws + 89 * MB);
    float* rs   = (float*)(ws + 89 * MB + 262144);
    float* bqkv = (float*)(ws + 90 * MB);
    u16*   wpe_t = (u16*)(ws + 91 * MB);
    u16*   wbase = (u16*)(ws + 92 * MB);   // per layer 3145728 u16 (6MB)

    auto qkvt = [&](int l) { return wbase + (size_t)l * 3145728; };
    auto wot  = [&](int l) { return qkvt(l) + 786432; };
    auto w1t  = [&](int l) { return wot(l) + 262144; };
    auto w2t  = [&](int l) { return w1t(l) + 1048576; };

    // prep
    f2b_kernel<<<256, 256, 0, stream>>>(x, xb, 65536);
    wtrans_kernel<<<dim3(16, 1), 256, 0, stream>>>(Wpe, wpe_t, 32, 512);
    for (int l = 0; l < L_; l++) {
        wtrans_kernel<<<dim3(16, 16), 256, 0, stream>>>(Wq + (size_t)l * 262144, qkvt(l), 512, 512);
        wtrans_kernel<<<dim3(16, 16), 256, 0, stream>>>(Wk + (size_t)l * 262144, qkvt(l) + 262144, 512, 512);
        wtrans_kernel<<<dim3(16, 16), 256, 0, stream>>>(Wv + (size_t)l * 262144, qkvt(l) + 524288, 512, 512);
        wtrans_kernel<<<dim3(16, 16), 256, 0, stream>>>(Wo + (size_t)l * 262144, wot(l), 512, 512);
        wtrans_kernel<<<dim3(64, 16), 256, 0, stream>>>(W1 + (size_t)l * 1048576, w1t(l), 512, 2048);
        wtrans_kernel<<<dim3(16, 64), 256, 0, stream>>>(W2 + (size_t)l * 1048576, w2t(l), 2048, 512);
    }
    bcat_kernel<<<12, 256, 0, stream>>>(bq, bk, bv, bqkv);
    rope_table_kernel<<<256, 256, 0, stream>>>(rc, rs);

    // embed: hb = bf16(x @ W_pe + b_pe)
    gemm_kernel<0, 64, 0><<<dim3(8, 64), 256, 0, stream>>>(
        xb, wpe_t, bpe, hb, BS_, 512, 32, 32,
        (u16*)nullptr, (u16*)nullptr, (u16*)nullptr, (const float*)nullptr, (const float*)nullptr);

    for (int l = 0; l < L_; l++) {
        // fused QKV + rope + relayout
        gemm_kernel<0, 128, 1><<<dim3(12, 64), 256, 0, stream>>>(
            hb, qkvt(l), bqkv + l * 1536, (u16*)nullptr, BS_, 1536, 512, 512,
            qbb, kbb, vf16, rc, rs);
        vtrans_kernel<<<dim3(32, 32), 256, 0, stream>>>(vf16, vtb);
        attn_kernel<<<2048, 64, 0, stream>>>(qbb, kbb, vtb, vid, maskp,
                                             usame + l * H_, ucros + l * H_, ob);
        gemm_kernel<0, 64, 0><<<dim3(8, 64), 256, 0, stream>>>(
            ob, wot(l), bo + l * 512, tb, BS_, 512, 512, 512,
            (u16*)nullptr, (u16*)nullptr, (u16*)nullptr, (const float*)nullptr, (const float*)nullptr);
        ln_kernel<<<8192, 64, 0, stream>>>(hb, tb, g1 + l * 512, be1 + l * 512);
        gemm_kernel<1, 128, 0><<<dim3(16, 64), 256, 0, stream>>>(
            hb, w1t(l), b1f + l * 2048, fb, BS_, 2048, 512, 512,
            (u16*)nullptr, (u16*)nullptr, (u16*)nullptr, (const float*)nullptr, (const float*)nullptr);
        gemm_kernel<0, 64, 0><<<dim3(8, 64), 256, 0, stream>>>(
            fb, w2t(l), b2f + l * 512, tb, BS_, 512, 2048, 2048,
            (u16*)nullptr, (u16*)nullptr, (u16*)nullptr, (const float*)nullptr, (const float*)nullptr);
        ln_kernel<<<8192, 64, 0, stream>>>(hb, tb, g2 + l * 512, be2 + l * 512);
    }
    head_kernel<<<1024, 256, 0, stream>>>(hb, Whd, bhd, (float*)d_out);
}

// Round 5
// 583.215 us; speedup vs baseline: 1.6648x; 1.3108x over previous
//
#include <hip/hip_runtime.h>

typedef unsigned short u16;
typedef unsigned int   u32;
typedef __attribute__((ext_vector_type(8))) short bf16x8;
typedef __attribute__((ext_vector_type(4))) short bf16x4;
typedef __attribute__((ext_vector_type(4))) float f32x4;
typedef __attribute__((ext_vector_type(4))) int   i32x4;

constexpr int B_ = 4, S_ = 2048, D_ = 512, H_ = 8, L_ = 2, DFF_ = 2048;
constexpr int BS_ = B_ * S_;            // 8192 token rows
constexpr float SCALE_ = 0.125f;        // 1/sqrt(64)

__device__ __forceinline__ u16 f2bf(float f) {
    u32 u = __float_as_uint(f);
    u += 0x7fffu + ((u >> 16) & 1u);    // RTNE
    return (u16)(u >> 16);
}
__device__ __forceinline__ float bf2f(u16 u) {
    return __uint_as_float(((u32)u) << 16);
}
__device__ __forceinline__ u32 cvt_pk_bf16(float lo, float hi) {
    u32 d;
    asm volatile("v_cvt_pk_bf16_f32 %0, %1, %2" : "=v"(d) : "v"(lo), "v"(hi));
    return d;
}

// ---------------------------------------------------------------- weight transpose: Wt[n*K+k] = bf16(W[k*N+n])
__global__ __launch_bounds__(256)
void wtrans_kernel(const float* __restrict__ W, u16* __restrict__ Wt, int K, int N)
{
    __shared__ float tile[32][33];
    const int n0 = blockIdx.x * 32, k0 = blockIdx.y * 32;
    const int t = threadIdx.x;
#pragma unroll
    for (int i = 0; i < 4; i++) {
        int lin = i * 256 + t;
        int r = lin >> 5, c = lin & 31;
        tile[r][c] = W[(size_t)(k0 + r) * N + n0 + c];
    }
    __syncthreads();
#pragma unroll
    for (int i = 0; i < 4; i++) {
        int lin = i * 256 + t;
        int r = lin >> 5, c = lin & 31;
        Wt[(size_t)(n0 + r) * K + k0 + c] = f2bf(tile[c][r]);
    }
}

// ---------------------------------------------------------------- f32 -> bf16 bulk convert (for x)
__global__ __launch_bounds__(256)
void f2b_kernel(const float* __restrict__ in, u16* __restrict__ out, int n4)
{
    int i = blockIdx.x * 256 + threadIdx.x;
    if (i < n4) {
        float4 f = *reinterpret_cast<const float4*>(in + (size_t)i * 4);
        uint2 pk;
        pk.x = (u32)f2bf(f.x) | ((u32)f2bf(f.y) << 16);
        pk.y = (u32)f2bf(f.z) | ((u32)f2bf(f.w) << 16);
        *reinterpret_cast<uint2*>(out + (size_t)i * 4) = pk;
    }
}

// ---------------------------------------------------------------- bias concat for fused QKV
__global__ __launch_bounds__(256)
void bcat_kernel(const float* __restrict__ bq, const float* __restrict__ bk,
                 const float* __restrict__ bv, float* __restrict__ o)
{
    int idx = blockIdx.x * 256 + threadIdx.x;
    if (idx < L_ * 1536) {
        int l = idx / 1536, i = idx % 1536;
        float v = (i < 512) ? bq[l * 512 + i]
                : (i < 1024) ? bk[l * 512 + i - 512]
                             : bv[l * 512 + i - 1024];
        o[idx] = v;
    }
}

// ---------------------------------------------------------------- rope tables (f32, [s][32] for cos/sin)
__global__ __launch_bounds__(256)
void rope_table_kernel(float* __restrict__ rc, float* __restrict__ rs)
{
    int idx = blockIdx.x * 256 + threadIdx.x;   // S_*32 = 65536
    int j = idx & 31, tpos = idx >> 5;
    float inv = __expf(-(float)j * 0.28782313662425572f);  // 10000^(-j/32)
    float ang = (float)tpos * inv;
    rc[idx] = cosf(ang);
    rs[idx] = sinf(ang);
}

// ---------------------------------------------------------------- GEMM: C(bf16) = A(bf16,MxK,lda) @ Bt^T(bf16,NxK) + bias
// ACT=1: exact GELU.  ROPE=1 (BN=128, N=1536): fused rope + [b,h,s,d] relayout for q/k, v passthrough.
template<int ACT, int BN, int ROPE>
__global__ __launch_bounds__(256)
void gemm_kernel(const u16* __restrict__ A, const u16* __restrict__ Bt,
                 const float* __restrict__ bias, u16* __restrict__ C,
                 int M, int N, int K, int lda,
                 u16* __restrict__ qd, u16* __restrict__ kd, u16* __restrict__ vd,
                 const float* __restrict__ rc, const float* __restrict__ rs)
{
    constexpr int LDT = 40;                // padded u16 row stride
    constexpr int NI = BN / 32;
    __shared__ u16 As[128 * LDT];
    __shared__ u16 Bs[BN * LDT];
    const int t = threadIdx.x;
    const int m0 = blockIdx.y * 128, n0 = blockIdx.x * BN;
    const int lane = t & 63, w = t >> 6;
    const int wr = w >> 1, wc = w & 1;
    const int l15 = lane & 15, lhi = lane >> 4;

    f32x4 acc[4][NI];
#pragma unroll
    for (int i = 0; i < 4; i++)
#pragma unroll
        for (int j = 0; j < NI; j++)
#pragma unroll
            for (int r = 0; r < 4; r++) acc[i][j][r] = 0.f;

    for (int kt = 0; kt < K; kt += 32) {
#pragma unroll
        for (int i = 0; i < 2; i++) {                 // A: 128x32 u16 = 512 chunks
            int lin = i * 256 + t;
            int r = lin >> 2, c8 = (lin & 3) << 3;
            *reinterpret_cast<bf16x8*>(&As[r * LDT + c8]) =
                *reinterpret_cast<const bf16x8*>(A + (size_t)(m0 + r) * lda + kt + c8);
        }
#pragma unroll
        for (int i = 0; i < BN / 64; i++) {           // B: BNx32 u16
            int lin = i * 256 + t;
            int r = lin >> 2, c8 = (lin & 3) << 3;
            *reinterpret_cast<bf16x8*>(&Bs[r * LDT + c8]) =
                *reinterpret_cast<const bf16x8*>(Bt + (size_t)(n0 + r) * K + kt + c8);
        }
        __syncthreads();
        bf16x8 af[4], bfv[NI];
#pragma unroll
        for (int mi = 0; mi < 4; mi++)
            af[mi] = *reinterpret_cast<const bf16x8*>(&As[(wr * 64 + mi * 16 + l15) * LDT + lhi * 8]);
#pragma unroll
        for (int ni = 0; ni < NI; ni++)
            bfv[ni] = *reinterpret_cast<const bf16x8*>(&Bs[(wc * (BN / 2) + ni * 16 + l15) * LDT + lhi * 8]);
#pragma unroll
        for (int mi = 0; mi < 4; mi++)
#pragma unroll
            for (int ni = 0; ni < NI; ni++)
                acc[mi][ni] = __builtin_amdgcn_mfma_f32_16x16x32_bf16(af[mi], bfv[ni], acc[mi][ni], 0, 0, 0);
        __syncthreads();
    }

    float bb[NI];
#pragma unroll
    for (int ni = 0; ni < NI; ni++) bb[ni] = bias[n0 + wc * (BN / 2) + ni * 16 + l15];

    if (ROPE == 0) {
#pragma unroll
        for (int mi = 0; mi < 4; mi++) {
            int row = m0 + wr * 64 + mi * 16 + lhi * 4;
#pragma unroll
            for (int ni = 0; ni < NI; ni++) {
                int col = n0 + wc * (BN / 2) + ni * 16 + l15;
#pragma unroll
                for (int r = 0; r < 4; r++) {
                    float v = acc[mi][ni][r] + bb[ni];
                    if (ACT == 1) v = 0.5f * v * (1.0f + erff(v * 0.70710678118654752f));
                    C[(size_t)(row + r) * N + col] = f2bf(v);
                }
            }
        }
    } else {
#pragma unroll
        for (int ni = 0; ni < NI; ni++) {
            int colb = n0 + wc * (BN / 2) + ni * 16;
            int region = colb >> 9;                    // 0=q,1=k,2=v (block-uniform)
            int col = colb + l15;
            int d = col & 63;
            int head = (col >> 6) & 7;
#pragma unroll
            for (int mi = 0; mi < 4; mi++) {
#pragma unroll
                for (int r = 0; r < 4; r++) {
                    int row = m0 + wr * 64 + mi * 16 + lhi * 4 + r;
                    int sp = row & (S_ - 1);
                    int bidx = row >> 11;
                    float v = acc[mi][ni][r] + bb[ni];
                    if (region == 2) {
                        vd[(size_t)row * 512 + (col - 1024)] = f2bf(v);
                    } else {
                        float px = __shfl_xor(v, 1);
                        int f = d & 30;
                        float cs = rc[sp * 32 + f], sn = rs[sp * 32 + f];
                        float ov = (l15 & 1) ? fmaf(px, sn, v * cs)
                                             : fmaf(v, cs, -(px * sn));
                        if (region == 0) ov *= SCALE_;
                        u16* dst = (region == 0) ? qd : kd;
                        dst[((size_t)(bidx * 8 + head) * S_ + sp) * 64 + d] = f2bf(ov);
                    }
                }
            }
        }
    }
}

// ---------------------------------------------------------------- V transpose: bf16 [row][512] -> bf16 [b,h,d,s]
__global__ __launch_bounds__(256)
void vtrans_kernel(const u16* __restrict__ vin, u16* __restrict__ vout)
{
    __shared__ u16 tile[64][72];
    const int bh = blockIdx.y, b = bh >> 3, hh = bh & 7;
    const int s0 = blockIdx.x * 64;
    const int t = threadIdx.x;
#pragma unroll
    for (int i = 0; i < 4; i++) {
        int lin = i * 256 + t;
        int r = lin >> 4, c4 = (lin & 15) << 2;
        *reinterpret_cast<uint2*>(&tile[r][c4]) =
            *reinterpret_cast<const uint2*>(vin + (size_t)(b * S_ + s0 + r) * 512 + hh * 64 + c4);
    }
    __syncthreads();
#pragma unroll
    for (int i = 0; i < 4; i++) {
        int lin = i * 256 + t;
        int d = lin >> 4, c4 = (lin & 15) << 2;
        uint2 pk;
        pk.x = (u32)tile[c4 + 0][d] | ((u32)tile[c4 + 1][d] << 16);
        pk.y = (u32)tile[c4 + 2][d] | ((u32)tile[c4 + 3][d] << 16);
        *reinterpret_cast<uint2*>(vout + ((size_t)bh * 64 + d) * S_ + s0 + c4) = pk;
    }
}

// ---------------------------------------------------------------- flash attention
// 4 waves / block, 128 Q-rows per block (32 per wave), shared LDS K & V^T tiles
// (64x64 bf16 each, double-buffered, XOR-swizzled byte^=((row&7)<<4)),
// staged via global_load_lds(16B) with pre-swizzled global source.
// Swapped-QK softmax in-register, defer-max THR=8, XCD-pinned swizzle.
__global__ __launch_bounds__(256)
void attn_kernel(const u16* __restrict__ qbp, const u16* __restrict__ kbp,
                 const u16* __restrict__ vt, const int* __restrict__ vid,
                 const float* __restrict__ maskp,
                 const float* __restrict__ usame, const float* __restrict__ ucross,
                 u16* __restrict__ o)
{
    __shared__ u16 ldsK[2][64 * 64];
    __shared__ u16 ldsV[2][64 * 64];
    const int bidx = blockIdx.x;            // 512 blocks
    const int xcd = bidx & 7;
    const int j = bidx >> 3;                // 0..63
    const int bh = xcd * 4 + (j >> 4);      // 4 heads pinned per XCD (2MB L2 set)
    const int chunk = j & 15;
    const int b = bh >> 3, hh = bh & 7;
    const int t = threadIdx.x;
    const int lane = t & 63, wid = t >> 6;
    const int q0 = chunk * 128 + wid * 32;
    const int l15 = lane & 15, lhi = lane >> 4;
    const int sw = (l15 & 7) << 4;          // per-lane read-swizzle XOR (bytes)
    const int ssw = ((t >> 3) & 7) << 4;    // per-thread stage-swizzle XOR (bytes)
    const u16* qp = qbp + (size_t)bh * S_ * 64;
    const u16* kp = kbp + (size_t)bh * S_ * 64;
    const u16* vp = vt + (size_t)bh * 64 * S_;
    const float us = usame[hh], uc = ucross[hh];
    const int* vidb = vid + (size_t)b * S_;
    const float* mkb = maskp + (size_t)b * S_;

    // --- stage: K tile is 8KB contiguous; V^T rows stride 4096B. Linear LDS dest,
    // pre-swizzled global source (so LDS[x^swz] = G[x]; reads use addr x^swz). ---
    auto stage = [&](int kv0, int buf) {
        const char* kg = (const char*)kp + (size_t)kv0 * 128;
#pragma unroll
        for (int p = 0; p < 2; p++) {
            int off = p * 4096 + t * 16;
            int so = off ^ ssw;
            __builtin_amdgcn_global_load_lds(
                (const __attribute__((address_space(1))) void*)(kg + so),
                (__attribute__((address_space(3))) void*)((char*)&ldsK[buf][0] + off), 16, 0, 0);
        }
        const char* vg = (const char*)vp + (size_t)kv0 * 2;
#pragma unroll
        for (int p = 0; p < 2; p++) {
            int off = p * 4096 + t * 16;
            int so = off ^ ssw;
            int row = so >> 7, colb = so & 127;
            __builtin_amdgcn_global_load_lds(
                (const __attribute__((address_space(1))) void*)(vg + (size_t)row * 4096 + colb),
                (__attribute__((address_space(3))) void*)((char*)&ldsV[buf][0] + off), 16, 0, 0);
        }
    };

    bf16x8 qfr[2][2];
#pragma unroll
    for (int mi = 0; mi < 2; mi++)
#pragma unroll
        for (int kk = 0; kk < 2; kk++)
            qfr[mi][kk] = *reinterpret_cast<const bf16x8*>(
                qp + (size_t)(q0 + mi * 16 + l15) * 64 + kk * 32 + lhi * 8);

    const int vq[2] = { vidb[q0 + l15], vidb[q0 + 16 + l15] };

    float mrow[2] = { -1e30f, -1e30f }, lrow[2] = { 0.f, 0.f };
    f32x4 oT[4][2];
#pragma unroll
    for (int nd = 0; nd < 4; nd++)
#pragma unroll
        for (int mi = 0; mi < 2; mi++)
#pragma unroll
            for (int r = 0; r < 4; r++) oT[nd][mi][r] = 0.f;

    stage(0, 0);
    __syncthreads();
    int cur = 0;

    for (int tt = 0; tt < S_ / 64; ++tt) {
        const int kv0 = tt * 64;
        if (tt < S_ / 64 - 1) stage(kv0 + 64, cur ^ 1);

        const u16* Kb = ldsK[cur];
        const u16* Vb = ldsV[cur];

        // ---- QK^T (swapped): sacc[ni][mi], lane holds S^T[k][q] ----
        f32x4 sacc[4][2];
#pragma unroll
        for (int ni = 0; ni < 4; ni++) {
            int rowb = (ni * 16 + l15) * 128;
            bf16x8 kf0 = *reinterpret_cast<const bf16x8*>((const char*)Kb + ((rowb + lhi * 16) ^ sw));
            bf16x8 kf1 = *reinterpret_cast<const bf16x8*>((const char*)Kb + ((rowb + 64 + lhi * 16) ^ sw));
#pragma unroll
            for (int mi = 0; mi < 2; mi++) {
#pragma unroll
                for (int r = 0; r < 4; r++) sacc[ni][mi][r] = 0.f;
                sacc[ni][mi] = __builtin_amdgcn_mfma_f32_16x16x32_bf16(kf0, qfr[mi][0], sacc[ni][mi], 0, 0, 0);
                sacc[ni][mi] = __builtin_amdgcn_mfma_f32_16x16x32_bf16(kf1, qfr[mi][1], sacc[ni][mi], 0, 0, 0);
            }
        }

        // ---- bias + mask ----
        i32x4 vkq[4]; f32x4 mdq[4];
#pragma unroll
        for (int ni = 0; ni < 4; ni++) {
            vkq[ni] = *reinterpret_cast<const i32x4*>(vidb + kv0 + ni * 16 + lhi * 4);
            f32x4 mm = *reinterpret_cast<const f32x4*>(mkb + kv0 + ni * 16 + lhi * 4);
#pragma unroll
            for (int r = 0; r < 4; r++) mdq[ni][r] = (1.0f - mm[r]) * -1e9f;
        }
#pragma unroll
        for (int mi = 0; mi < 2; mi++)
#pragma unroll
            for (int ni = 0; ni < 4; ni++)
#pragma unroll
                for (int r = 0; r < 4; r++)
                    sacc[ni][mi][r] += mdq[ni][r] + ((vkq[ni][r] == vq[mi]) ? us : uc);

        // ---- online softmax (lane-local rows, 2 shfl per 16 q-rows), defer-max ----
        bf16x4 pb[2][4];
#pragma unroll
        for (int mi = 0; mi < 2; mi++) {
            float pm = sacc[0][mi][0];
#pragma unroll
            for (int ni = 0; ni < 4; ni++)
#pragma unroll
                for (int r = 0; r < 4; r++)
                    if (ni || r) pm = fmaxf(pm, sacc[ni][mi][r]);
            pm = fmaxf(pm, __shfl_xor(pm, 16));
            pm = fmaxf(pm, __shfl_xor(pm, 32));
            if (!__all(pm <= mrow[mi] + 8.f)) {
                float mnew = fmaxf(mrow[mi], pm);
                float alpha = __expf(mrow[mi] - mnew);
                mrow[mi] = mnew;
                lrow[mi] *= alpha;
#pragma unroll
                for (int nd = 0; nd < 4; nd++)
#pragma unroll
                    for (int r = 0; r < 4; r++) oT[nd][mi][r] *= alpha;
            }
            float ps[4][4];
#pragma unroll
            for (int ni = 0; ni < 4; ni++)
#pragma unroll
                for (int r = 0; r < 4; r++)
                    ps[ni][r] = __expf(sacc[ni][mi][r] - mrow[mi]);
            float rsum = ((ps[0][0] + ps[0][1]) + (ps[0][2] + ps[0][3]))
                       + ((ps[1][0] + ps[1][1]) + (ps[1][2] + ps[1][3]))
                       + ((ps[2][0] + ps[2][1]) + (ps[2][2] + ps[2][3]))
                       + ((ps[3][0] + ps[3][1]) + (ps[3][2] + ps[3][3]));
            rsum += __shfl_xor(rsum, 16);
            rsum += __shfl_xor(rsum, 32);
            lrow[mi] += rsum;
#pragma unroll
            for (int ni = 0; ni < 4; ni++) {
                union { u32 u[2]; bf16x4 h; } uu;
                uu.u[0] = cvt_pk_bf16(ps[ni][0], ps[ni][1]);
                uu.u[1] = cvt_pk_bf16(ps[ni][2], ps[ni][3]);
                pb[mi][ni] = uu.h;
            }
        }

        // ---- PV: O^T += V^T · P  (nd-major, vf reused across both mi) ----
#pragma unroll
        for (int nd = 0; nd < 4; nd++) {
            int rowb = (nd * 16 + l15) * 128;
            bf16x4 vf[4];
#pragma unroll
            for (int ni = 0; ni < 4; ni++)
                vf[ni] = *reinterpret_cast<const bf16x4*>((const char*)Vb + ((rowb + ni * 32 + lhi * 8) ^ sw));
#pragma unroll
            for (int mi = 0; mi < 2; mi++)
#pragma unroll
                for (int ni = 0; ni < 4; ni++)
                    oT[nd][mi] = __builtin_amdgcn_mfma_f32_16x16x16bf16_1k(vf[ni], pb[mi][ni], oT[nd][mi], 0, 0, 0);
        }

        __syncthreads();          // drains this iter's stage (vmcnt) + protects buffers
        cur ^= 1;
    }

#pragma unroll
    for (int mi = 0; mi < 2; mi++) {
        float inv = 1.0f / lrow[mi];
        size_t rowb = (size_t)(b * S_ + q0 + mi * 16 + l15) * D_;
#pragma unroll
        for (int nd = 0; nd < 4; nd++) {
            uint2 st;
            st.x = cvt_pk_bf16(oT[nd][mi][0] * inv, oT[nd][mi][1] * inv);
            st.y = cvt_pk_bf16(oT[nd][mi][2] * inv, oT[nd][mi][3] * inv);
            *reinterpret_cast<uint2*>(o + rowb + hh * 64 + nd * 16 + lhi * 4) = st;
        }
    }
}

// ---------------------------------------------------------------- LayerNorm: hb = LN(hb + t)*g + be  (bf16 in/out)
__global__ __launch_bounds__(64)
void ln_kernel(u16* hb, const u16* __restrict__ tb,
               const float* __restrict__ g, const float* __restrict__ be)
{
    const int row = blockIdx.x;
    const int lane = threadIdx.x;
    u16* hp = hb + (size_t)row * D_ + lane * 8;
    const u16* tp = tb + (size_t)row * D_ + lane * 8;
    bf16x8 a = *reinterpret_cast<const bf16x8*>(hp);
    bf16x8 c = *reinterpret_cast<const bf16x8*>(tp);
    float x[8];
    float s = 0.f, s2 = 0.f;
#pragma unroll
    for (int j = 0; j < 8; j++) {
        x[j] = bf2f((u16)a[j]) + bf2f((u16)c[j]);
        s += x[j]; s2 += x[j] * x[j];
    }
#pragma unroll
    for (int m = 1; m <= 32; m <<= 1) { s += __shfl_xor(s, m); s2 += __shfl_xor(s2, m); }
    float mean = s * (1.0f / 512.0f);
    float var = s2 * (1.0f / 512.0f) - mean * mean;
    float rstd = rsqrtf(var + 1e-5f);
    const float* gp = g + lane * 8;
    const float* bp = be + lane * 8;
    bf16x8 ov;
#pragma unroll
    for (int j = 0; j < 8; j++)
        ov[j] = (short)f2bf((x[j] - mean) * rstd * gp[j] + bp[j]);
    *reinterpret_cast<bf16x8*>(hp) = ov;
}

// ---------------------------------------------------------------- head: out(f32) = hb(bf16) @ Wh + bh  (N=32)
__global__ __launch_bounds__(256)
void head_kernel(const u16* __restrict__ hb, const float* __restrict__ Wh,
                 const float* __restrict__ bhv, float* __restrict__ out)
{
    const int t = threadIdx.x;
    const int p = t & 31, sub = t >> 5;
    const int row = blockIdx.x * 8 + sub;
    const u16* hp = hb + (size_t)row * D_;
    float acc = 0.f;
#pragma unroll 4
    for (int k0 = 0; k0 < D_; k0 += 8) {
        bf16x8 hv = *reinterpret_cast<const bf16x8*>(hp + k0);
#pragma unroll
        for (int j = 0; j < 8; j++)
            acc = fmaf(bf2f((u16)hv[j]), Wh[(size_t)(k0 + j) * 32 + p], acc);
    }
    out[(size_t)row * 32 + p] = acc + bhv[p];
}

// ---------------------------------------------------------------- launch
extern "C" void kernel_launch(void* const* d_in, const int* in_sizes, int n_in,
                              void* d_out, int out_size, void* d_ws, size_t ws_size,
                              hipStream_t stream)
{
    (void)in_sizes; (void)n_in; (void)out_size; (void)ws_size;
    const float* x     = (const float*)d_in[0];
    const int*   vid   = (const int*)d_in[1];
    const float* maskp = (const float*)d_in[2];
    const float* Wpe   = (const float*)d_in[3];
    const float* bpe   = (const float*)d_in[4];
    const float* Wq    = (const float*)d_in[5];
    const float* bq    = (const float*)d_in[6];
    const float* Wk    = (const float*)d_in[7];
    const float* bk    = (const float*)d_in[8];
    const float* Wv    = (const float*)d_in[9];
    const float* bv    = (const float*)d_in[10];
    const float* Wo    = (const float*)d_in[11];
    const float* bo    = (const float*)d_in[12];
    const float* usame = (const float*)d_in[13];
    const float* ucros = (const float*)d_in[14];
    const float* g1    = (const float*)d_in[15];
    const float* be1   = (const float*)d_in[16];
    const float* W1    = (const float*)d_in[17];
    const float* b1f   = (const float*)d_in[18];
    const float* W2    = (const float*)d_in[19];
    const float* b2f   = (const float*)d_in[20];
    const float* g2    = (const float*)d_in[21];
    const float* be2   = (const float*)d_in[22];
    const float* Whd   = (const float*)d_in[23];
    const float* bhd   = (const float*)d_in[24];

    constexpr size_t MB = 1024ull * 1024ull;
    char* ws = (char*)d_ws;
    u16*   hb   = (u16*)(ws + 0);          // 8 MB
    u16*   qbb  = (u16*)(ws + 8 * MB);     // 8 MB [b,h,s,64], pre-scaled
    u16*   kbb  = (u16*)(ws + 16 * MB);    // 8 MB [b,h,s,64]
    u16*   vf16 = (u16*)(ws + 24 * MB);    // 8 MB [row][512]
    u16*   vtb  = (u16*)(ws + 32 * MB);    // 8 MB [b,h,d,s]
    u16*   ob   = (u16*)(ws + 40 * MB);    // 8 MB
    u16*   tb   = (u16*)(ws + 48 * MB);    // 8 MB
    u16*   fb   = (u16*)(ws + 56 * MB);    // 32 MB
    u16*   xb   = (u16*)(ws + 88 * MB);    // 0.5 MB
    float* rc   = (float*)(ws + 89 * MB);
    float* rs   = (float*)(ws + 89 * MB + 262144);
    float* bqkv = (float*)(ws + 90 * MB);
    u16*   wpe_t = (u16*)(ws + 91 * MB);
    u16*   wbase = (u16*)(ws + 92 * MB);   // per layer 3145728 u16 (6MB)

    auto qkvt = [&](int l) { return wbase + (size_t)l * 3145728; };
    auto wot  = [&](int l) { return qkvt(l) + 786432; };
    auto w1t  = [&](int l) { return wot(l) + 262144; };
    auto w2t  = [&](int l) { return w1t(l) + 1048576; };

    // prep
    f2b_kernel<<<256, 256, 0, stream>>>(x, xb, 65536);
    wtrans_kernel<<<dim3(16, 1), 256, 0, stream>>>(Wpe, wpe_t, 32, 512);
    for (int l = 0; l < L_; l++) {
        wtrans_kernel<<<dim3(16, 16), 256, 0, stream>>>(Wq + (size_t)l * 262144, qkvt(l), 512, 512);
        wtrans_kernel<<<dim3(16, 16), 256, 0, stream>>>(Wk + (size_t)l * 262144, qkvt(l) + 262144, 512, 512);
        wtrans_kernel<<<dim3(16, 16), 256, 0, stream>>>(Wv + (size_t)l * 262144, qkvt(l) + 524288, 512, 512);
        wtrans_kernel<<<dim3(16, 16), 256, 0, stream>>>(Wo + (size_t)l * 262144, wot(l), 512, 512);
        wtrans_kernel<<<dim3(64, 16), 256, 0, stream>>>(W1 + (size_t)l * 1048576, w1t(l), 512, 2048);
        wtrans_kernel<<<dim3(16, 64), 256, 0, stream>>>(W2 + (size_t)l * 1048576, w2t(l), 2048, 512);
    }
    bcat_kernel<<<12, 256, 0, stream>>>(bq, bk, bv, bqkv);
    rope_table_kernel<<<256, 256, 0, stream>>>(rc, rs);

    // embed: hb = bf16(x @ W_pe + b_pe)
    gemm_kernel<0, 64, 0><<<dim3(8, 64), 256, 0, stream>>>(
        xb, wpe_t, bpe, hb, BS_, 512, 32, 32,
        (u16*)nullptr, (u16*)nullptr, (u16*)nullptr, (const float*)nullptr, (const float*)nullptr);

    for (int l = 0; l < L_; l++) {
        // fused QKV + rope + relayout
        gemm_kernel<0, 128, 1><<<dim3(12, 64), 256, 0, stream>>>(
            hb, qkvt(l), bqkv + l * 1536, (u16*)nullptr, BS_, 1536, 512, 512,
            qbb, kbb, vf16, rc, rs);
        vtrans_kernel<<<dim3(32, 32), 256, 0, stream>>>(vf16, vtb);
        attn_kernel<<<512, 256, 0, stream>>>(qbb, kbb, vtb, vid, maskp,
                                             usame + l * H_, ucros + l * H_, ob);
        gemm_kernel<0, 64, 0><<<dim3(8, 64), 256, 0, stream>>>(
            ob, wot(l), bo + l * 512, tb, BS_, 512, 512, 512,
            (u16*)nullptr, (u16*)nullptr, (u16*)nullptr, (const float*)nullptr, (const float*)nullptr);
        ln_kernel<<<8192, 64, 0, stream>>>(hb, tb, g1 + l * 512, be1 + l * 512);
        gemm_kernel<1, 128, 0><<<dim3(16, 64), 256, 0, stream>>>(
            hb, w1t(l), b1f + l * 2048, fb, BS_, 2048, 512, 512,
            (u16*)nullptr, (u16*)nullptr, (u16*)nullptr, (const float*)nullptr, (const float*)nullptr);
        gemm_kernel<0, 64, 0><<<dim3(8, 64), 256, 0, stream>>>(
            fb, w2t(l), b2f + l * 512, tb, BS_, 512, 2048, 2048,
            (u16*)nullptr, (u16*)nullptr, (u16*)nullptr, (const float*)nullptr, (const float*)nullptr);
        ln_kernel<<<8192, 64, 0, stream>>>(hb, tb, g2 + l * 512, be2 + l * 512);
    }
    head_kernel<<<1024, 256, 0, stream>>>(hb, Whd, bhd, (float*)d_out);
}

// Round 6
// 523.187 us; speedup vs baseline: 1.8558x; 1.1147x over previous
//
#include <hip/hip_runtime.h>

typedef unsigned short u16;
typedef unsigned int   u32;
typedef __attribute__((ext_vector_type(8))) short bf16x8;
typedef __attribute__((ext_vector_type(4))) short bf16x4;
typedef __attribute__((ext_vector_type(4))) float f32x4;
typedef __attribute__((ext_vector_type(4))) int   i32x4;

constexpr int B_ = 4, S_ = 2048, D_ = 512, H_ = 8, L_ = 2, DFF_ = 2048;
constexpr int BS_ = B_ * S_;            // 8192 token rows
constexpr float QSC_ = 0.18033688011f;  // (1/sqrt(64)) * log2(e)
constexpr float LOG2E_ = 1.44269504089f;

__device__ __forceinline__ u16 f2bf(float f) {
    u32 u = __float_as_uint(f);
    u += 0x7fffu + ((u >> 16) & 1u);    // RTNE
    return (u16)(u >> 16);
}
__device__ __forceinline__ float bf2f(u16 u) {
    return __uint_as_float(((u32)u) << 16);
}
__device__ __forceinline__ u32 cvt_pk_bf16(float lo, float hi) {
    u32 d;
    asm volatile("v_cvt_pk_bf16_f32 %0, %1, %2" : "=v"(d) : "v"(lo), "v"(hi));
    return d;
}
__device__ __forceinline__ float exp2v(float x) {   // 2^x via v_exp_f32
    float d;
    asm("v_exp_f32 %0, %1" : "=v"(d) : "v"(x));
    return d;
}

// ---------------------------------------------------------------- weight transpose: Wt[n*K+k] = bf16(W[k*N+n])
__global__ __launch_bounds__(256)
void wtrans_kernel(const float* __restrict__ W, u16* __restrict__ Wt, int K, int N)
{
    __shared__ float tile[32][33];
    const int n0 = blockIdx.x * 32, k0 = blockIdx.y * 32;
    const int t = threadIdx.x;
#pragma unroll
    for (int i = 0; i < 4; i++) {
        int lin = i * 256 + t;
        int r = lin >> 5, c = lin & 31;
        tile[r][c] = W[(size_t)(k0 + r) * N + n0 + c];
    }
    __syncthreads();
#pragma unroll
    for (int i = 0; i < 4; i++) {
        int lin = i * 256 + t;
        int r = lin >> 5, c = lin & 31;
        Wt[(size_t)(n0 + r) * K + k0 + c] = f2bf(tile[c][r]);
    }
}

// ---------------------------------------------------------------- f32 -> bf16 bulk convert (for x)
__global__ __launch_bounds__(256)
void f2b_kernel(const float* __restrict__ in, u16* __restrict__ out, int n4)
{
    int i = blockIdx.x * 256 + threadIdx.x;
    if (i < n4) {
        float4 f = *reinterpret_cast<const float4*>(in + (size_t)i * 4);
        uint2 pk;
        pk.x = (u32)f2bf(f.x) | ((u32)f2bf(f.y) << 16);
        pk.y = (u32)f2bf(f.z) | ((u32)f2bf(f.w) << 16);
        *reinterpret_cast<uint2*>(out + (size_t)i * 4) = pk;
    }
}

// ---------------------------------------------------------------- bias concat for fused QKV
__global__ __launch_bounds__(256)
void bcat_kernel(const float* __restrict__ bq, const float* __restrict__ bk,
                 const float* __restrict__ bv, float* __restrict__ o)
{
    int idx = blockIdx.x * 256 + threadIdx.x;
    if (idx < L_ * 1536) {
        int l = idx / 1536, i = idx % 1536;
        float v = (i < 512) ? bq[l * 512 + i]
                : (i < 1024) ? bk[l * 512 + i - 512]
                             : bv[l * 512 + i - 1024];
        o[idx] = v;
    }
}

// ---------------------------------------------------------------- rope tables (f32, [s][32] for cos/sin)
__global__ __launch_bounds__(256)
void rope_table_kernel(float* __restrict__ rc, float* __restrict__ rs)
{
    int idx = blockIdx.x * 256 + threadIdx.x;   // S_*32 = 65536
    int j = idx & 31, tpos = idx >> 5;
    float inv = __expf(-(float)j * 0.28782313662425572f);  // 10000^(-j/32)
    float ang = (float)tpos * inv;
    rc[idx] = cosf(ang);
    rs[idx] = sinf(ang);
}

// ---------------------------------------------------------------- legacy GEMM (register-staged, BK=32) — used only for embed (K=32)
template<int ACT, int BN, int ROPE>
__global__ __launch_bounds__(256)
void gemm_kernel(const u16* __restrict__ A, const u16* __restrict__ Bt,
                 const float* __restrict__ bias, u16* __restrict__ C,
                 int M, int N, int K, int lda,
                 u16* __restrict__ qd, u16* __restrict__ kd, u16* __restrict__ vd,
                 const float* __restrict__ rc, const float* __restrict__ rs)
{
    constexpr int LDT = 40;
    constexpr int NI = BN / 32;
    __shared__ u16 As[128 * LDT];
    __shared__ u16 Bs[BN * LDT];
    const int t = threadIdx.x;
    const int m0 = blockIdx.y * 128, n0 = blockIdx.x * BN;
    const int lane = t & 63, w = t >> 6;
    const int wr = w >> 1, wc = w & 1;
    const int l15 = lane & 15, lhi = lane >> 4;

    f32x4 acc[4][NI];
#pragma unroll
    for (int i = 0; i < 4; i++)
#pragma unroll
        for (int j = 0; j < NI; j++)
#pragma unroll
            for (int r = 0; r < 4; r++) acc[i][j][r] = 0.f;

    for (int kt = 0; kt < K; kt += 32) {
#pragma unroll
        for (int i = 0; i < 2; i++) {
            int lin = i * 256 + t;
            int r = lin >> 2, c8 = (lin & 3) << 3;
            *reinterpret_cast<bf16x8*>(&As[r * LDT + c8]) =
                *reinterpret_cast<const bf16x8*>(A + (size_t)(m0 + r) * lda + kt + c8);
        }
#pragma unroll
        for (int i = 0; i < BN / 64; i++) {
            int lin = i * 256 + t;
            int r = lin >> 2, c8 = (lin & 3) << 3;
            *reinterpret_cast<bf16x8*>(&Bs[r * LDT + c8]) =
                *reinterpret_cast<const bf16x8*>(Bt + (size_t)(n0 + r) * K + kt + c8);
        }
        __syncthreads();
        bf16x8 af[4], bfv[NI];
#pragma unroll
        for (int mi = 0; mi < 4; mi++)
            af[mi] = *reinterpret_cast<const bf16x8*>(&As[(wr * 64 + mi * 16 + l15) * LDT + lhi * 8]);
#pragma unroll
        for (int ni = 0; ni < NI; ni++)
            bfv[ni] = *reinterpret_cast<const bf16x8*>(&Bs[(wc * (BN / 2) + ni * 16 + l15) * LDT + lhi * 8]);
#pragma unroll
        for (int mi = 0; mi < 4; mi++)
#pragma unroll
            for (int ni = 0; ni < NI; ni++)
                acc[mi][ni] = __builtin_amdgcn_mfma_f32_16x16x32_bf16(af[mi], bfv[ni], acc[mi][ni], 0, 0, 0);
        __syncthreads();
    }

    float bb[NI];
#pragma unroll
    for (int ni = 0; ni < NI; ni++) bb[ni] = bias[n0 + wc * (BN / 2) + ni * 16 + l15];
#pragma unroll
    for (int mi = 0; mi < 4; mi++) {
        int row = m0 + wr * 64 + mi * 16 + lhi * 4;
#pragma unroll
        for (int ni = 0; ni < NI; ni++) {
            int col = n0 + wc * (BN / 2) + ni * 16 + l15;
#pragma unroll
            for (int r = 0; r < 4; r++) {
                float v = acc[mi][ni][r] + bb[ni];
                if (ACT == 1) v = 0.5f * v * (1.0f + erff(v * 0.70710678118654752f));
                C[(size_t)(row + r) * N + col] = f2bf(v);
            }
        }
    }
}

// ---------------------------------------------------------------- main GEMM: double-buffered, global_load_lds staged, BK=64,
// XOR-swizzled LDS (byte ^= (row&7)<<4, pre-swizzled global source).
// C(bf16) = A(bf16,MxK,lda) @ Bt^T(bf16,NxK) + bias; ACT=1: GELU;
// ROPE=1 (BN=128, N=1536): fused rope + [b,h,s,d] relayout (q pre-scaled by QSC_).
template<int ACT, int BN, int ROPE>
__global__ __launch_bounds__(256)
void gemm_db(const u16* __restrict__ A, const u16* __restrict__ Bt,
             const float* __restrict__ bias, u16* __restrict__ C,
             int M, int N, int K, int lda,
             u16* __restrict__ qd, u16* __restrict__ kd, u16* __restrict__ vd,
             const float* __restrict__ rc, const float* __restrict__ rs)
{
    constexpr int NI = BN / 32;
    constexpr int ABYTES = 128 * 128;       // 128 rows x 64 u16
    constexpr int BBYTES = BN * 128;
    constexpr int HALF = ABYTES + BBYTES;
    __shared__ char lds[2 * HALF];
    const int t = threadIdx.x;
    const int m0 = blockIdx.y * 128, n0 = blockIdx.x * BN;
    const int lane = t & 63, w = t >> 6;
    const int wr = w >> 1, wc = w & 1;
    const int l15 = lane & 15, lhi = lane >> 4;
    const int sw = (l15 & 7) << 4;

    auto stage = [&](int kt, int buf) {
        char* base = lds + buf * HALF;
#pragma unroll
        for (int p = 0; p < ABYTES / 4096; p++) {
            int off = p * 4096 + t * 16;
            int so = off ^ (((off >> 7) & 7) << 4);   // row bits unchanged by xor
            int row = off >> 7;
            int col = (so & 127) >> 1;
            __builtin_amdgcn_global_load_lds(
                (const __attribute__((address_space(1))) void*)(A + (size_t)(m0 + row) * lda + kt + col),
                (__attribute__((address_space(3))) void*)(base + off), 16, 0, 0);
        }
        char* bb = base + ABYTES;
#pragma unroll
        for (int p = 0; p < BBYTES / 4096; p++) {
            int off = p * 4096 + t * 16;
            int so = off ^ (((off >> 7) & 7) << 4);
            int row = off >> 7;
            int col = (so & 127) >> 1;
            __builtin_amdgcn_global_load_lds(
                (const __attribute__((address_space(1))) void*)(Bt + (size_t)(n0 + row) * K + kt + col),
                (__attribute__((address_space(3))) void*)(bb + off), 16, 0, 0);
        }
    };

    f32x4 acc[4][NI];
#pragma unroll
    for (int i = 0; i < 4; i++)
#pragma unroll
        for (int j = 0; j < NI; j++)
#pragma unroll
            for (int r = 0; r < 4; r++) acc[i][j][r] = 0.f;

    stage(0, 0);
    __syncthreads();
    int buf = 0;
    for (int kt = 0; kt < K; kt += 64) {
        if (kt + 64 < K) stage(kt + 64, buf ^ 1);
        const char* La = lds + buf * HALF;
        const char* Lb = La + ABYTES;
        bf16x8 af[4][2], bfv[NI][2];
#pragma unroll
        for (int mi = 0; mi < 4; mi++) {
            int row = wr * 64 + mi * 16 + l15;
#pragma unroll
            for (int kk = 0; kk < 2; kk++)
                af[mi][kk] = *reinterpret_cast<const bf16x8*>(La + ((row * 128 + kk * 64 + lhi * 16) ^ sw));
        }
#pragma unroll
        for (int ni = 0; ni < NI; ni++) {
            int row = wc * (BN / 2) + ni * 16 + l15;
#pragma unroll
            for (int kk = 0; kk < 2; kk++)
                bfv[ni][kk] = *reinterpret_cast<const bf16x8*>(Lb + ((row * 128 + kk * 64 + lhi * 16) ^ sw));
        }
#pragma unroll
        for (int kk = 0; kk < 2; kk++)
#pragma unroll
            for (int mi = 0; mi < 4; mi++)
#pragma unroll
                for (int ni = 0; ni < NI; ni++)
                    acc[mi][ni] = __builtin_amdgcn_mfma_f32_16x16x32_bf16(af[mi][kk], bfv[ni][kk], acc[mi][ni], 0, 0, 0);
        __syncthreads();          // drains stage vmcnt + protects buffer reuse
        buf ^= 1;
    }

    float bb[NI];
#pragma unroll
    for (int ni = 0; ni < NI; ni++) bb[ni] = bias[n0 + wc * (BN / 2) + ni * 16 + l15];

    if (ROPE == 0) {
#pragma unroll
        for (int mi = 0; mi < 4; mi++) {
            int row = m0 + wr * 64 + mi * 16 + lhi * 4;
#pragma unroll
            for (int ni = 0; ni < NI; ni++) {
                int col = n0 + wc * (BN / 2) + ni * 16 + l15;
#pragma unroll
                for (int r = 0; r < 4; r++) {
                    float v = acc[mi][ni][r] + bb[ni];
                    if (ACT == 1) v = 0.5f * v * (1.0f + erff(v * 0.70710678118654752f));
                    C[(size_t)(row + r) * N + col] = f2bf(v);
                }
            }
        }
    } else {
#pragma unroll
        for (int ni = 0; ni < NI; ni++) {
            int colb = n0 + wc * (BN / 2) + ni * 16;
            int region = colb >> 9;                    // 0=q,1=k,2=v (block-uniform)
            int col = colb + l15;
            int d = col & 63;
            int head = (col >> 6) & 7;
#pragma unroll
            for (int mi = 0; mi < 4; mi++) {
#pragma unroll
                for (int r = 0; r < 4; r++) {
                    int row = m0 + wr * 64 + mi * 16 + lhi * 4 + r;
                    int sp = row & (S_ - 1);
                    int bidx = row >> 11;
                    float v = acc[mi][ni][r] + bb[ni];
                    if (region == 2) {
                        vd[(size_t)row * 512 + (col - 1024)] = f2bf(v);
                    } else {
                        float px = __shfl_xor(v, 1);
                        int f = d & 30;
                        float cs = rc[sp * 32 + f], sn = rs[sp * 32 + f];
                        float ov = (l15 & 1) ? fmaf(px, sn, v * cs)
                                             : fmaf(v, cs, -(px * sn));
                        if (region == 0) ov *= QSC_;   // fold 1/sqrt(d) * log2e into q
                        u16* dst = (region == 0) ? qd : kd;
                        dst[((size_t)(bidx * 8 + head) * S_ + sp) * 64 + d] = f2bf(ov);
                    }
                }
            }
        }
    }
}

// ---------------------------------------------------------------- V transpose: bf16 [row][512] -> bf16 [b,h,d,s]
__global__ __launch_bounds__(256)
void vtrans_kernel(const u16* __restrict__ vin, u16* __restrict__ vout)
{
    __shared__ u16 tile[64][72];
    const int bh = blockIdx.y, b = bh >> 3, hh = bh & 7;
    const int s0 = blockIdx.x * 64;
    const int t = threadIdx.x;
#pragma unroll
    for (int i = 0; i < 4; i++) {
        int lin = i * 256 + t;
        int r = lin >> 4, c4 = (lin & 15) << 2;
        *reinterpret_cast<uint2*>(&tile[r][c4]) =
            *reinterpret_cast<const uint2*>(vin + (size_t)(b * S_ + s0 + r) * 512 + hh * 64 + c4);
    }
    __syncthreads();
#pragma unroll
    for (int i = 0; i < 4; i++) {
        int lin = i * 256 + t;
        int d = lin >> 4, c4 = (lin & 15) << 2;
        uint2 pk;
        pk.x = (u32)tile[c4 + 0][d] | ((u32)tile[c4 + 1][d] << 16);
        pk.y = (u32)tile[c4 + 2][d] | ((u32)tile[c4 + 3][d] << 16);
        *reinterpret_cast<uint2*>(vout + ((size_t)bh * 64 + d) * S_ + s0 + c4) = pk;
    }
}

// ---------------------------------------------------------------- flash attention (log2-domain softmax)
// 4 waves / block, 128 Q-rows per block, shared LDS K & V^T tiles (64x64 bf16,
// double-buffered, XOR-swizzled), staged via global_load_lds(16B).
// Swapped-QK softmax in-register, defer-max, XCD-pinned swizzle.
__global__ __launch_bounds__(256)
void attn_kernel(const u16* __restrict__ qbp, const u16* __restrict__ kbp,
                 const u16* __restrict__ vt, const int* __restrict__ vid,
                 const float* __restrict__ maskp,
                 const float* __restrict__ usame, const float* __restrict__ ucross,
                 u16* __restrict__ o)
{
    __shared__ u16 ldsK[2][64 * 64];
    __shared__ u16 ldsV[2][64 * 64];
    const int bidx = blockIdx.x;            // 512 blocks
    const int xcd = bidx & 7;
    const int j = bidx >> 3;                // 0..63
    const int bh = xcd * 4 + (j >> 4);      // 4 heads pinned per XCD (2MB L2 set)
    const int chunk = j & 15;
    const int b = bh >> 3, hh = bh & 7;
    const int t = threadIdx.x;
    const int lane = t & 63, wid = t >> 6;
    const int q0 = chunk * 128 + wid * 32;
    const int l15 = lane & 15, lhi = lane >> 4;
    const int sw = (l15 & 7) << 4;          // per-lane read-swizzle XOR (bytes)
    const int ssw = ((t >> 3) & 7) << 4;    // per-thread stage-swizzle XOR (bytes)
    const u16* qp = qbp + (size_t)bh * S_ * 64;
    const u16* kp = kbp + (size_t)bh * S_ * 64;
    const u16* vp = vt + (size_t)bh * 64 * S_;
    const float us = usame[hh] * LOG2E_, uc = ucross[hh] * LOG2E_;
    const int* vidb = vid + (size_t)b * S_;
    const float* mkb = maskp + (size_t)b * S_;

    auto stage = [&](int kv0, int buf) {
        const char* kg = (const char*)kp + (size_t)kv0 * 128;
#pragma unroll
        for (int p = 0; p < 2; p++) {
            int off = p * 4096 + t * 16;
            int so = off ^ ssw;
            __builtin_amdgcn_global_load_lds(
                (const __attribute__((address_space(1))) void*)(kg + so),
                (__attribute__((address_space(3))) void*)((char*)&ldsK[buf][0] + off), 16, 0, 0);
        }
        const char* vg = (const char*)vp + (size_t)kv0 * 2;
#pragma unroll
        for (int p = 0; p < 2; p++) {
            int off = p * 4096 + t * 16;
            int so = off ^ ssw;
            int row = so >> 7, colb = so & 127;
            __builtin_amdgcn_global_load_lds(
                (const __attribute__((address_space(1))) void*)(vg + (size_t)row * 4096 + colb),
                (__attribute__((address_space(3))) void*)((char*)&ldsV[buf][0] + off), 16, 0, 0);
        }
    };

    bf16x8 qfr[2][2];
#pragma unroll
    for (int mi = 0; mi < 2; mi++)
#pragma unroll
        for (int kk = 0; kk < 2; kk++)
            qfr[mi][kk] = *reinterpret_cast<const bf16x8*>(
                qp + (size_t)(q0 + mi * 16 + l15) * 64 + kk * 32 + lhi * 8);

    const int vq[2] = { vidb[q0 + l15], vidb[q0 + 16 + l15] };

    float mrow[2] = { -1e30f, -1e30f }, lrow[2] = { 0.f, 0.f };
    f32x4 oT[4][2];
#pragma unroll
    for (int nd = 0; nd < 4; nd++)
#pragma unroll
        for (int mi = 0; mi < 2; mi++)
#pragma unroll
            for (int r = 0; r < 4; r++) oT[nd][mi][r] = 0.f;

    stage(0, 0);
    __syncthreads();
    int cur = 0;

    for (int tt = 0; tt < S_ / 64; ++tt) {
        const int kv0 = tt * 64;
        if (tt < S_ / 64 - 1) stage(kv0 + 64, cur ^ 1);

        const u16* Kb = ldsK[cur];
        const u16* Vb = ldsV[cur];

        // ---- QK^T (swapped): sacc[ni][mi], lane holds S^T[k][q], log2 units ----
        f32x4 sacc[4][2];
#pragma unroll
        for (int ni = 0; ni < 4; ni++) {
            int rowb = (ni * 16 + l15) * 128;
            bf16x8 kf0 = *reinterpret_cast<const bf16x8*>((const char*)Kb + ((rowb + lhi * 16) ^ sw));
            bf16x8 kf1 = *reinterpret_cast<const bf16x8*>((const char*)Kb + ((rowb + 64 + lhi * 16) ^ sw));
#pragma unroll
            for (int mi = 0; mi < 2; mi++) {
#pragma unroll
                for (int r = 0; r < 4; r++) sacc[ni][mi][r] = 0.f;
                sacc[ni][mi] = __builtin_amdgcn_mfma_f32_16x16x32_bf16(kf0, qfr[mi][0], sacc[ni][mi], 0, 0, 0);
                sacc[ni][mi] = __builtin_amdgcn_mfma_f32_16x16x32_bf16(kf1, qfr[mi][1], sacc[ni][mi], 0, 0, 0);
            }
        }

        // ---- bias + mask (log2-scaled) ----
        i32x4 vkq[4]; f32x4 mdq[4];
#pragma unroll
        for (int ni = 0; ni < 4; ni++) {
            vkq[ni] = *reinterpret_cast<const i32x4*>(vidb + kv0 + ni * 16 + lhi * 4);
            f32x4 mm = *reinterpret_cast<const f32x4*>(mkb + kv0 + ni * 16 + lhi * 4);
#pragma unroll
            for (int r = 0; r < 4; r++) mdq[ni][r] = (1.0f - mm[r]) * -1.44269504e9f;
        }
#pragma unroll
        for (int mi = 0; mi < 2; mi++)
#pragma unroll
            for (int ni = 0; ni < 4; ni++)
#pragma unroll
                for (int r = 0; r < 4; r++)
                    sacc[ni][mi][r] += mdq[ni][r] + ((vkq[ni][r] == vq[mi]) ? us : uc);

        // ---- online softmax in log2 domain, defer-max ----
        bf16x4 pb[2][4];
#pragma unroll
        for (int mi = 0; mi < 2; mi++) {
            float pm = sacc[0][mi][0];
#pragma unroll
            for (int ni = 0; ni < 4; ni++)
#pragma unroll
                for (int r = 0; r < 4; r++)
                    if (ni || r) pm = fmaxf(pm, sacc[ni][mi][r]);
            pm = fmaxf(pm, __shfl_xor(pm, 16));
            pm = fmaxf(pm, __shfl_xor(pm, 32));
            if (!__all(pm <= mrow[mi] + 8.f)) {
                float mnew = fmaxf(mrow[mi], pm);
                float alpha = exp2v(mrow[mi] - mnew);
                mrow[mi] = mnew;
                lrow[mi] *= alpha;
#pragma unroll
                for (int nd = 0; nd < 4; nd++)
#pragma unroll
                    for (int r = 0; r < 4; r++) oT[nd][mi][r] *= alpha;
            }
            float ps[4][4];
#pragma unroll
            for (int ni = 0; ni < 4; ni++)
#pragma unroll
                for (int r = 0; r < 4; r++)
                    ps[ni][r] = exp2v(sacc[ni][mi][r] - mrow[mi]);
            float rsum = ((ps[0][0] + ps[0][1]) + (ps[0][2] + ps[0][3]))
                       + ((ps[1][0] + ps[1][1]) + (ps[1][2] + ps[1][3]))
                       + ((ps[2][0] + ps[2][1]) + (ps[2][2] + ps[2][3]))
                       + ((ps[3][0] + ps[3][1]) + (ps[3][2] + ps[3][3]));
            rsum += __shfl_xor(rsum, 16);
            rsum += __shfl_xor(rsum, 32);
            lrow[mi] += rsum;
#pragma unroll
            for (int ni = 0; ni < 4; ni++) {
                union { u32 u[2]; bf16x4 h; } uu;
                uu.u[0] = cvt_pk_bf16(ps[ni][0], ps[ni][1]);
                uu.u[1] = cvt_pk_bf16(ps[ni][2], ps[ni][3]);
                pb[mi][ni] = uu.h;
            }
        }

        // ---- PV: O^T += V^T · P ----
#pragma unroll
        for (int nd = 0; nd < 4; nd++) {
            int rowb = (nd * 16 + l15) * 128;
            bf16x4 vf[4];
#pragma unroll
            for (int ni = 0; ni < 4; ni++)
                vf[ni] = *reinterpret_cast<const bf16x4*>((const char*)Vb + ((rowb + ni * 32 + lhi * 8) ^ sw));
#pragma unroll
            for (int mi = 0; mi < 2; mi++)
#pragma unroll
                for (int ni = 0; ni < 4; ni++)
                    oT[nd][mi] = __builtin_amdgcn_mfma_f32_16x16x16bf16_1k(vf[ni], pb[mi][ni], oT[nd][mi], 0, 0, 0);
        }

        __syncthreads();
        cur ^= 1;
    }

#pragma unroll
    for (int mi = 0; mi < 2; mi++) {
        float inv = 1.0f / lrow[mi];
        size_t rowb = (size_t)(b * S_ + q0 + mi * 16 + l15) * D_;
#pragma unroll
        for (int nd = 0; nd < 4; nd++) {
            uint2 st;
            st.x = cvt_pk_bf16(oT[nd][mi][0] * inv, oT[nd][mi][1] * inv);
            st.y = cvt_pk_bf16(oT[nd][mi][2] * inv, oT[nd][mi][3] * inv);
            *reinterpret_cast<uint2*>(o + rowb + hh * 64 + nd * 16 + lhi * 4) = st;
        }
    }
}

// ---------------------------------------------------------------- LayerNorm: hb = LN(hb + t)*g + be  (bf16 in/out)
__global__ __launch_bounds__(64)
void ln_kernel(u16* hb, const u16* __restrict__ tb,
               const float* __restrict__ g, const float* __restrict__ be)
{
    const int row = blockIdx.x;
    const int lane = threadIdx.x;
    u16* hp = hb + (size_t)row * D_ + lane * 8;
    const u16* tp = tb + (size_t)row * D_ + lane * 8;
    bf16x8 a = *reinterpret_cast<const bf16x8*>(hp);
    bf16x8 c = *reinterpret_cast<const bf16x8*>(tp);
    float x[8];
    float s = 0.f, s2 = 0.f;
#pragma unroll
    for (int j = 0; j < 8; j++) {
        x[j] = bf2f((u16)a[j]) + bf2f((u16)c[j]);
        s += x[j]; s2 += x[j] * x[j];
    }
#pragma unroll
    for (int m = 1; m <= 32; m <<= 1) { s += __shfl_xor(s, m); s2 += __shfl_xor(s2, m); }
    float mean = s * (1.0f / 512.0f);
    float var = s2 * (1.0f / 512.0f) - mean * mean;
    float rstd = rsqrtf(var + 1e-5f);
    const float* gp = g + lane * 8;
    const float* bp = be + lane * 8;
    bf16x8 ov;
#pragma unroll
    for (int j = 0; j < 8; j++)
        ov[j] = (short)f2bf((x[j] - mean) * rstd * gp[j] + bp[j]);
    *reinterpret_cast<bf16x8*>(hp) = ov;
}

// ---------------------------------------------------------------- head: out(f32) = hb(bf16) @ Wh + bh  (N=32)
__global__ __launch_bounds__(256)
void head_kernel(const u16* __restrict__ hb, const float* __restrict__ Wh,
                 const float* __restrict__ bhv, float* __restrict__ out)
{
    const int t = threadIdx.x;
    const int p = t & 31, sub = t >> 5;
    const int row = blockIdx.x * 8 + sub;
    const u16* hp = hb + (size_t)row * D_;
    float acc = 0.f;
#pragma unroll 4
    for (int k0 = 0; k0 < D_; k0 += 8) {
        bf16x8 hv = *reinterpret_cast<const bf16x8*>(hp + k0);
#pragma unroll
        for (int j = 0; j < 8; j++)
            acc = fmaf(bf2f((u16)hv[j]), Wh[(size_t)(k0 + j) * 32 + p], acc);
    }
    out[(size_t)row * 32 + p] = acc + bhv[p];
}

// ---------------------------------------------------------------- launch
extern "C" void kernel_launch(void* const* d_in, const int* in_sizes, int n_in,
                              void* d_out, int out_size, void* d_ws, size_t ws_size,
                              hipStream_t stream)
{
    (void)in_sizes; (void)n_in; (void)out_size; (void)ws_size;
    const float* x     = (const float*)d_in[0];
    const int*   vid   = (const int*)d_in[1];
    const float* maskp = (const float*)d_in[2];
    const float* Wpe   = (const float*)d_in[3];
    const float* bpe   = (const float*)d_in[4];
    const float* Wq    = (const float*)d_in[5];
    const float* bq    = (const float*)d_in[6];
    const float* Wk    = (const float*)d_in[7];
    const float* bk    = (const float*)d_in[8];
    const float* Wv    = (const float*)d_in[9];
    const float* bv    = (const float*)d_in[10];
    const float* Wo    = (const float*)d_in[11];
    const float* bo    = (const float*)d_in[12];
    const float* usame = (const float*)d_in[13];
    const float* ucros = (const float*)d_in[14];
    const float* g1    = (const float*)d_in[15];
    const float* be1   = (const float*)d_in[16];
    const float* W1    = (const float*)d_in[17];
    const float* b1f   = (const float*)d_in[18];
    const float* W2    = (const float*)d_in[19];
    const float* b2f   = (const float*)d_in[20];
    const float* g2    = (const float*)d_in[21];
    const float* be2   = (const float*)d_in[22];
    const float* Whd   = (const float*)d_in[23];
    const float* bhd   = (const float*)d_in[24];

    constexpr size_t MB = 1024ull * 1024ull;
    char* ws = (char*)d_ws;
    u16*   hb   = (u16*)(ws + 0);          // 8 MB
    u16*   qbb  = (u16*)(ws + 8 * MB);     // 8 MB [b,h,s,64], pre-scaled by QSC_
    u16*   kbb  = (u16*)(ws + 16 * MB);    // 8 MB [b,h,s,64]
    u16*   vf16 = (u16*)(ws + 24 * MB);    // 8 MB [row][512]
    u16*   vtb  = (u16*)(ws + 32 * MB);    // 8 MB [b,h,d,s]
    u16*   ob   = (u16*)(ws + 40 * MB);    // 8 MB
    u16*   tb   = (u16*)(ws + 48 * MB);    // 8 MB
    u16*   fb   = (u16*)(ws + 56 * MB);    // 32 MB
    u16*   xb   = (u16*)(ws + 88 * MB);    // 0.5 MB
    float* rc   = (float*)(ws + 89 * MB);
    float* rs   = (float*)(ws + 89 * MB + 262144);
    float* bqkv = (float*)(ws + 90 * MB);
    u16*   wpe_t = (u16*)(ws + 91 * MB);
    u16*   wbase = (u16*)(ws + 92 * MB);   // per layer 3145728 u16 (6MB)

    auto qkvt = [&](int l) { return wbase + (size_t)l * 3145728; };
    auto wot  = [&](int l) { return qkvt(l) + 786432; };
    auto w1t  = [&](int l) { return wot(l) + 262144; };
    auto w2t  = [&](int l) { return w1t(l) + 1048576; };

    // prep
    f2b_kernel<<<256, 256, 0, stream>>>(x, xb, 65536);
    wtrans_kernel<<<dim3(16, 1), 256, 0, stream>>>(Wpe, wpe_t, 32, 512);
    for (int l = 0; l < L_; l++) {
        wtrans_kernel<<<dim3(16, 16), 256, 0, stream>>>(Wq + (size_t)l * 262144, qkvt(l), 512, 512);
        wtrans_kernel<<<dim3(16, 16), 256, 0, stream>>>(Wk + (size_t)l * 262144, qkvt(l) + 262144, 512, 512);
        wtrans_kernel<<<dim3(16, 16), 256, 0, stream>>>(Wv + (size_t)l * 262144, qkvt(l) + 524288, 512, 512);
        wtrans_kernel<<<dim3(16, 16), 256, 0, stream>>>(Wo + (size_t)l * 262144, wot(l), 512, 512);
        wtrans_kernel<<<dim3(64, 16), 256, 0, stream>>>(W1 + (size_t)l * 1048576, w1t(l), 512, 2048);
        wtrans_kernel<<<dim3(16, 64), 256, 0, stream>>>(W2 + (size_t)l * 1048576, w2t(l), 2048, 512);
    }
    bcat_kernel<<<12, 256, 0, stream>>>(bq, bk, bv, bqkv);
    rope_table_kernel<<<256, 256, 0, stream>>>(rc, rs);

    // embed: hb = bf16(x @ W_pe + b_pe)  (K=32, legacy path)
    gemm_kernel<0, 64, 0><<<dim3(8, 64), 256, 0, stream>>>(
        xb, wpe_t, bpe, hb, BS_, 512, 32, 32,
        (u16*)nullptr, (u16*)nullptr, (u16*)nullptr, (const float*)nullptr, (const float*)nullptr);

    for (int l = 0; l < L_; l++) {
        // fused QKV + rope + relayout
        gemm_db<0, 128, 1><<<dim3(12, 64), 256, 0, stream>>>(
            hb, qkvt(l), bqkv + l * 1536, (u16*)nullptr, BS_, 1536, 512, 512,
            qbb, kbb, vf16, rc, rs);
        vtrans_kernel<<<dim3(32, 32), 256, 0, stream>>>(vf16, vtb);
        attn_kernel<<<512, 256, 0, stream>>>(qbb, kbb, vtb, vid, maskp,
                                             usame + l * H_, ucros + l * H_, ob);
        gemm_db<0, 64, 0><<<dim3(8, 64), 256, 0, stream>>>(
            ob, wot(l), bo + l * 512, tb, BS_, 512, 512, 512,
            (u16*)nullptr, (u16*)nullptr, (u16*)nullptr, (const float*)nullptr, (const float*)nullptr);
        ln_kernel<<<8192, 64, 0, stream>>>(hb, tb, g1 + l * 512, be1 + l * 512);
        gemm_db<1, 128, 0><<<dim3(16, 64), 256, 0, stream>>>(
            hb, w1t(l), b1f + l * 2048, fb, BS_, 2048, 512, 512,
            (u16*)nullptr, (u16*)nullptr, (u16*)nullptr, (const float*)nullptr, (const float*)nullptr);
        gemm_db<0, 64, 0><<<dim3(8, 64), 256, 0, stream>>>(
            fb, w2t(l), b2f + l * 512, tb, BS_, 512, 2048, 2048,
            (u16*)nullptr, (u16*)nullptr, (u16*)nullptr, (const float*)nullptr, (const float*)nullptr);
        ln_kernel<<<8192, 64, 0, stream>>>(hb, tb, g2 + l * 512, be2 + l * 512);
    }
    head_kernel<<<1024, 256, 0, stream>>>(hb, Whd, bhd, (float*)d_out);
}

// Round 7
// 484.089 us; speedup vs baseline: 2.0057x; 1.0808x over previous
//
#include <hip/hip_runtime.h>

typedef unsigned short u16;
typedef unsigned int   u32;
typedef __attribute__((ext_vector_type(8))) short bf16x8;
typedef __attribute__((ext_vector_type(4))) short bf16x4;
typedef __attribute__((ext_vector_type(4))) float f32x4;
typedef __attribute__((ext_vector_type(4))) int   i32x4;

constexpr int B_ = 4, S_ = 2048, D_ = 512, H_ = 8, L_ = 2, DFF_ = 2048;
constexpr int BS_ = B_ * S_;            // 8192 token rows
constexpr float QSC_ = 0.18033688011f;  // (1/sqrt(64)) * log2(e)
constexpr float LOG2E_ = 1.44269504089f;

__device__ __forceinline__ u16 f2bf(float f) {
    u32 u = __float_as_uint(f);
    u += 0x7fffu + ((u >> 16) & 1u);    // RTNE
    return (u16)(u >> 16);
}
__device__ __forceinline__ float bf2f(u16 u) {
    return __uint_as_float(((u32)u) << 16);
}
__device__ __forceinline__ u32 cvt_pk_bf16(float lo, float hi) {
    u32 d;
    asm volatile("v_cvt_pk_bf16_f32 %0, %1, %2" : "=v"(d) : "v"(lo), "v"(hi));
    return d;
}
__device__ __forceinline__ float exp2v(float x) {   // 2^x via v_exp_f32
    float d;
    asm("v_exp_f32 %0, %1" : "=v"(d) : "v"(x));
    return d;
}
__device__ __forceinline__ float max3v(float a, float b, float c) {
    float d;
    asm("v_max3_f32 %0, %1, %2, %3" : "=v"(d) : "v"(a), "v"(b), "v"(c));
    return d;
}

// ---------------------------------------------------------------- all weight transposes in ONE dispatch
// Wt[n*K+k] = bf16(W[k*N+n]) for: Wpe(32x512), {Wq,Wk,Wv,Wo}x2 (512x512),
// W1 x2 (512x2048), W2 x2 (2048x512).  Grid = 16 + 2048 + 2048 + 2048 = 6160.
__global__ __launch_bounds__(256)
void wtrans_all(const float* __restrict__ Wpe, const float* __restrict__ Wq,
                const float* __restrict__ Wk, const float* __restrict__ Wv,
                const float* __restrict__ Wo, const float* __restrict__ W1,
                const float* __restrict__ W2, u16* __restrict__ wpe_t,
                u16* __restrict__ wbase)
{
    __shared__ float tile[32][33];
    int id = blockIdx.x;
    const float* src; u16* dst; int K, N, tx, ty;
    if (id < 16) {
        src = Wpe; dst = wpe_t; K = 32; N = 512; tx = id; ty = 0;
    } else {
        id -= 16;
        if (id < 2048) {                       // Wq/Wk/Wv/Wo, 256 tiles each
            int mat = id >> 8, l = mat >> 2, w = mat & 3;
            const float* srcs[4] = { Wq, Wk, Wv, Wo };
            src = srcs[w] + (size_t)l * 262144;
            u16* base = wbase + (size_t)l * 3145728;
            dst = base + (size_t)w * 262144;   // q,k,v at 0/256K/512K; wo at 768K
            K = 512; N = 512;
            int t8 = id & 255; tx = t8 & 15; ty = t8 >> 4;
        } else if (id < 4096) {                // W1: K=512, N=2048
            id -= 2048;
            int l = id >> 10, t = id & 1023;
            src = W1 + (size_t)l * 1048576;
            dst = wbase + (size_t)l * 3145728 + 1048576;
            K = 512; N = 2048; tx = t & 63; ty = t >> 6;
        } else {                               // W2: K=2048, N=512
            id -= 4096;
            int l = id >> 10, t = id & 1023;
            src = W2 + (size_t)l * 1048576;
            dst = wbase + (size_t)l * 3145728 + 2097152;
            K = 2048; N = 512; tx = t & 15; ty = t >> 4;
        }
    }
    const int n0 = tx * 32, k0 = ty * 32;
    const int t = threadIdx.x;
#pragma unroll
    for (int i = 0; i < 4; i++) {
        int lin = i * 256 + t;
        int r = lin >> 5, c = lin & 31;
        tile[r][c] = src[(size_t)(k0 + r) * N + n0 + c];
    }
    __syncthreads();
#pragma unroll
    for (int i = 0; i < 4; i++) {
        int lin = i * 256 + t;
        int r = lin >> 5, c = lin & 31;
        dst[(size_t)(n0 + r) * K + k0 + c] = f2bf(tile[c][r]);
    }
}

// ---------------------------------------------------------------- misc prep: rope tables + x->bf16 + bias concat (one dispatch)
// grid 524: [0,256) rope, [256,512) f2b, [512,524) bcat
__global__ __launch_bounds__(256)
void misc_prep(const float* __restrict__ x, u16* __restrict__ xb,
               const float* __restrict__ bq, const float* __restrict__ bk,
               const float* __restrict__ bv, float* __restrict__ bqkv,
               float* __restrict__ rc, float* __restrict__ rs)
{
    const int id = blockIdx.x, t = threadIdx.x;
    if (id < 256) {
        int idx = id * 256 + t;                 // 65536
        int j = idx & 31, tpos = idx >> 5;
        float inv = __expf(-(float)j * 0.28782313662425572f);
        float ang = (float)tpos * inv;
        rc[idx] = cosf(ang);
        rs[idx] = sinf(ang);
    } else if (id < 512) {
        int i = (id - 256) * 256 + t;           // 65536 float4s
        float4 f = *reinterpret_cast<const float4*>(x + (size_t)i * 4);
        uint2 pk;
        pk.x = (u32)f2bf(f.x) | ((u32)f2bf(f.y) << 16);
        pk.y = (u32)f2bf(f.z) | ((u32)f2bf(f.w) << 16);
        *reinterpret_cast<uint2*>(xb + (size_t)i * 4) = pk;
    } else {
        int idx = (id - 512) * 256 + t;
        if (idx < L_ * 1536) {
            int l = idx / 1536, i = idx % 1536;
            float v = (i < 512) ? bq[l * 512 + i]
                    : (i < 1024) ? bk[l * 512 + i - 512]
                                 : bv[l * 512 + i - 1024];
            bqkv[idx] = v;
        }
    }
}

// ---------------------------------------------------------------- legacy GEMM (register-staged, BK=32) — used only for embed (K=32)
template<int ACT, int BN, int ROPE>
__global__ __launch_bounds__(256)
void gemm_kernel(const u16* __restrict__ A, const u16* __restrict__ Bt,
                 const float* __restrict__ bias, u16* __restrict__ C,
                 int M, int N, int K, int lda,
                 u16* __restrict__ qd, u16* __restrict__ kd, u16* __restrict__ vd,
                 const float* __restrict__ rc, const float* __restrict__ rs)
{
    constexpr int LDT = 40;
    constexpr int NI = BN / 32;
    __shared__ u16 As[128 * LDT];
    __shared__ u16 Bs[BN * LDT];
    const int t = threadIdx.x;
    const int m0 = blockIdx.y * 128, n0 = blockIdx.x * BN;
    const int lane = t & 63, w = t >> 6;
    const int wr = w >> 1, wc = w & 1;
    const int l15 = lane & 15, lhi = lane >> 4;

    f32x4 acc[4][NI];
#pragma unroll
    for (int i = 0; i < 4; i++)
#pragma unroll
        for (int j = 0; j < NI; j++)
#pragma unroll
            for (int r = 0; r < 4; r++) acc[i][j][r] = 0.f;

    for (int kt = 0; kt < K; kt += 32) {
#pragma unroll
        for (int i = 0; i < 2; i++) {
            int lin = i * 256 + t;
            int r = lin >> 2, c8 = (lin & 3) << 3;
            *reinterpret_cast<bf16x8*>(&As[r * LDT + c8]) =
                *reinterpret_cast<const bf16x8*>(A + (size_t)(m0 + r) * lda + kt + c8);
        }
#pragma unroll
        for (int i = 0; i < BN / 64; i++) {
            int lin = i * 256 + t;
            int r = lin >> 2, c8 = (lin & 3) << 3;
            *reinterpret_cast<bf16x8*>(&Bs[r * LDT + c8]) =
                *reinterpret_cast<const bf16x8*>(Bt + (size_t)(n0 + r) * K + kt + c8);
        }
        __syncthreads();
        bf16x8 af[4], bfv[NI];
#pragma unroll
        for (int mi = 0; mi < 4; mi++)
            af[mi] = *reinterpret_cast<const bf16x8*>(&As[(wr * 64 + mi * 16 + l15) * LDT + lhi * 8]);
#pragma unroll
        for (int ni = 0; ni < NI; ni++)
            bfv[ni] = *reinterpret_cast<const bf16x8*>(&Bs[(wc * (BN / 2) + ni * 16 + l15) * LDT + lhi * 8]);
#pragma unroll
        for (int mi = 0; mi < 4; mi++)
#pragma unroll
            for (int ni = 0; ni < NI; ni++)
                acc[mi][ni] = __builtin_amdgcn_mfma_f32_16x16x32_bf16(af[mi], bfv[ni], acc[mi][ni], 0, 0, 0);
        __syncthreads();
    }

    float bb[NI];
#pragma unroll
    for (int ni = 0; ni < NI; ni++) bb[ni] = bias[n0 + wc * (BN / 2) + ni * 16 + l15];
#pragma unroll
    for (int mi = 0; mi < 4; mi++) {
        int row = m0 + wr * 64 + mi * 16 + lhi * 4;
#pragma unroll
        for (int ni = 0; ni < NI; ni++) {
            int col = n0 + wc * (BN / 2) + ni * 16 + l15;
#pragma unroll
            for (int r = 0; r < 4; r++) {
                float v = acc[mi][ni][r] + bb[ni];
                if (ACT == 1) v = 0.5f * v * (1.0f + erff(v * 0.70710678118654752f));
                C[(size_t)(row + r) * N + col] = f2bf(v);
            }
        }
    }
}

// ---------------------------------------------------------------- main GEMM: double-buffered, global_load_lds staged, BK=64,
// XOR-swizzled LDS (byte ^= (row&7)<<4, pre-swizzled global source).
template<int ACT, int BN, int ROPE>
__global__ __launch_bounds__(256)
void gemm_db(const u16* __restrict__ A, const u16* __restrict__ Bt,
             const float* __restrict__ bias, u16* __restrict__ C,
             int M, int N, int K, int lda,
             u16* __restrict__ qd, u16* __restrict__ kd, u16* __restrict__ vd,
             const float* __restrict__ rc, const float* __restrict__ rs)
{
    constexpr int NI = BN / 32;
    constexpr int ABYTES = 128 * 128;       // 128 rows x 64 u16
    constexpr int BBYTES = BN * 128;
    constexpr int HALF = ABYTES + BBYTES;
    __shared__ char lds[2 * HALF];
    const int t = threadIdx.x;
    const int m0 = blockIdx.y * 128, n0 = blockIdx.x * BN;
    const int lane = t & 63, w = t >> 6;
    const int wr = w >> 1, wc = w & 1;
    const int l15 = lane & 15, lhi = lane >> 4;
    const int sw = (l15 & 7) << 4;

    auto stage = [&](int kt, int buf) {
        char* base = lds + buf * HALF;
#pragma unroll
        for (int p = 0; p < ABYTES / 4096; p++) {
            int off = p * 4096 + t * 16;
            int so = off ^ (((off >> 7) & 7) << 4);   // row bits unchanged by xor
            int row = off >> 7;
            int col = (so & 127) >> 1;
            __builtin_amdgcn_global_load_lds(
                (const __attribute__((address_space(1))) void*)(A + (size_t)(m0 + row) * lda + kt + col),
                (__attribute__((address_space(3))) void*)(base + off), 16, 0, 0);
        }
        char* bb = base + ABYTES;
#pragma unroll
        for (int p = 0; p < BBYTES / 4096; p++) {
            int off = p * 4096 + t * 16;
            int so = off ^ (((off >> 7) & 7) << 4);
            int row = off >> 7;
            int col = (so & 127) >> 1;
            __builtin_amdgcn_global_load_lds(
                (const __attribute__((address_space(1))) void*)(Bt + (size_t)(n0 + row) * K + kt + col),
                (__attribute__((address_space(3))) void*)(bb + off), 16, 0, 0);
        }
    };

    f32x4 acc[4][NI];
#pragma unroll
    for (int i = 0; i < 4; i++)
#pragma unroll
        for (int j = 0; j < NI; j++)
#pragma unroll
            for (int r = 0; r < 4; r++) acc[i][j][r] = 0.f;

    stage(0, 0);
    __syncthreads();
    int buf = 0;
    for (int kt = 0; kt < K; kt += 64) {
        if (kt + 64 < K) stage(kt + 64, buf ^ 1);
        const char* La = lds + buf * HALF;
        const char* Lb = La + ABYTES;
        bf16x8 af[4][2], bfv[NI][2];
#pragma unroll
        for (int mi = 0; mi < 4; mi++) {
            int row = wr * 64 + mi * 16 + l15;
#pragma unroll
            for (int kk = 0; kk < 2; kk++)
                af[mi][kk] = *reinterpret_cast<const bf16x8*>(La + ((row * 128 + kk * 64 + lhi * 16) ^ sw));
        }
#pragma unroll
        for (int ni = 0; ni < NI; ni++) {
            int row = wc * (BN / 2) + ni * 16 + l15;
#pragma unroll
            for (int kk = 0; kk < 2; kk++)
                bfv[ni][kk] = *reinterpret_cast<const bf16x8*>(Lb + ((row * 128 + kk * 64 + lhi * 16) ^ sw));
        }
#pragma unroll
        for (int kk = 0; kk < 2; kk++)
#pragma unroll
            for (int mi = 0; mi < 4; mi++)
#pragma unroll
                for (int ni = 0; ni < NI; ni++)
                    acc[mi][ni] = __builtin_amdgcn_mfma_f32_16x16x32_bf16(af[mi][kk], bfv[ni][kk], acc[mi][ni], 0, 0, 0);
        __syncthreads();          // drains stage vmcnt + protects buffer reuse
        buf ^= 1;
    }

    float bb[NI];
#pragma unroll
    for (int ni = 0; ni < NI; ni++) bb[ni] = bias[n0 + wc * (BN / 2) + ni * 16 + l15];

    if (ROPE == 0) {
#pragma unroll
        for (int mi = 0; mi < 4; mi++) {
            int row = m0 + wr * 64 + mi * 16 + lhi * 4;
#pragma unroll
            for (int ni = 0; ni < NI; ni++) {
                int col = n0 + wc * (BN / 2) + ni * 16 + l15;
#pragma unroll
                for (int r = 0; r < 4; r++) {
                    float v = acc[mi][ni][r] + bb[ni];
                    if (ACT == 1) v = 0.5f * v * (1.0f + erff(v * 0.70710678118654752f));
                    C[(size_t)(row + r) * N + col] = f2bf(v);
                }
            }
        }
    } else {
#pragma unroll
        for (int ni = 0; ni < NI; ni++) {
            int colb = n0 + wc * (BN / 2) + ni * 16;
            int region = colb >> 9;                    // 0=q,1=k,2=v (block-uniform)
            int col = colb + l15;
            int d = col & 63;
            int head = (col >> 6) & 7;
#pragma unroll
            for (int mi = 0; mi < 4; mi++) {
#pragma unroll
                for (int r = 0; r < 4; r++) {
                    int row = m0 + wr * 64 + mi * 16 + lhi * 4 + r;
                    int sp = row & (S_ - 1);
                    int bidx = row >> 11;
                    float v = acc[mi][ni][r] + bb[ni];
                    if (region == 2) {
                        vd[(size_t)row * 512 + (col - 1024)] = f2bf(v);
                    } else {
                        float px = __shfl_xor(v, 1);
                        int f = d & 30;
                        float cs = rc[sp * 32 + f], sn = rs[sp * 32 + f];
                        float ov = (l15 & 1) ? fmaf(px, sn, v * cs)
                                             : fmaf(v, cs, -(px * sn));
                        if (region == 0) ov *= QSC_;   // fold 1/sqrt(d) * log2e into q
                        u16* dst = (region == 0) ? qd : kd;
                        dst[((size_t)(bidx * 8 + head) * S_ + sp) * 64 + d] = f2bf(ov);
                    }
                }
            }
        }
    }
}

// ---------------------------------------------------------------- V transpose: bf16 [row][512] -> bf16 [b,h,d,s]
__global__ __launch_bounds__(256)
void vtrans_kernel(const u16* __restrict__ vin, u16* __restrict__ vout)
{
    __shared__ u16 tile[64][72];
    const int bh = blockIdx.y, b = bh >> 3, hh = bh & 7;
    const int s0 = blockIdx.x * 64;
    const int t = threadIdx.x;
#pragma unroll
    for (int i = 0; i < 4; i++) {
        int lin = i * 256 + t;
        int r = lin >> 4, c4 = (lin & 15) << 2;
        *reinterpret_cast<uint2*>(&tile[r][c4]) =
            *reinterpret_cast<const uint2*>(vin + (size_t)(b * S_ + s0 + r) * 512 + hh * 64 + c4);
    }
    __syncthreads();
#pragma unroll
    for (int i = 0; i < 4; i++) {
        int lin = i * 256 + t;
        int d = lin >> 4, c4 = (lin & 15) << 2;
        uint2 pk;
        pk.x = (u32)tile[c4 + 0][d] | ((u32)tile[c4 + 1][d] << 16);
        pk.y = (u32)tile[c4 + 2][d] | ((u32)tile[c4 + 3][d] << 16);
        *reinterpret_cast<uint2*>(vout + ((size_t)bh * 64 + d) * S_ + s0 + c4) = pk;
    }
}

// ---------------------------------------------------------------- flash attention (log2-domain softmax)
// 4 waves / block, 128 Q-rows/block, LDS K & V^T tiles (64x64 bf16, dbuf,
// XOR-swizzled), global_load_lds staging, swapped-QK in-register softmax,
// defer-max, row-sum via MFMA-with-ones (l accumulated in matrix pipe),
// s_setprio around MFMA clusters, XCD-pinned block swizzle.
__global__ __launch_bounds__(256)
void attn_kernel(const u16* __restrict__ qbp, const u16* __restrict__ kbp,
                 const u16* __restrict__ vt, const int* __restrict__ vid,
                 const float* __restrict__ maskp,
                 const float* __restrict__ usame, const float* __restrict__ ucross,
                 u16* __restrict__ o)
{
    __shared__ u16 ldsK[2][64 * 64];
    __shared__ u16 ldsV[2][64 * 64];
    const int bidx = blockIdx.x;            // 512 blocks
    const int xcd = bidx & 7;
    const int j = bidx >> 3;                // 0..63
    const int bh = xcd * 4 + (j >> 4);      // 4 heads pinned per XCD (2MB L2 set)
    const int chunk = j & 15;
    const int b = bh >> 3, hh = bh & 7;
    const int t = threadIdx.x;
    const int lane = t & 63, wid = t >> 6;
    const int q0 = chunk * 128 + wid * 32;
    const int l15 = lane & 15, lhi = lane >> 4;
    const int sw = (l15 & 7) << 4;          // per-lane read-swizzle XOR (bytes)
    const int ssw = ((t >> 3) & 7) << 4;    // per-thread stage-swizzle XOR (bytes)
    const u16* qp = qbp + (size_t)bh * S_ * 64;
    const u16* kp = kbp + (size_t)bh * S_ * 64;
    const u16* vp = vt + (size_t)bh * 64 * S_;
    const float us = usame[hh] * LOG2E_, uc = ucross[hh] * LOG2E_;
    const int* vidb = vid + (size_t)b * S_;
    const float* mkb = maskp + (size_t)b * S_;
    const bf16x4 ones = { (short)0x3F80, (short)0x3F80, (short)0x3F80, (short)0x3F80 };

    auto stage = [&](int kv0, int buf) {
        const char* kg = (const char*)kp + (size_t)kv0 * 128;
#pragma unroll
        for (int p = 0; p < 2; p++) {
            int off = p * 4096 + t * 16;
            int so = off ^ ssw;
            __builtin_amdgcn_global_load_lds(
                (const __attribute__((address_space(1))) void*)(kg + so),
                (__attribute__((address_space(3))) void*)((char*)&ldsK[buf][0] + off), 16, 0, 0);
        }
        const char* vg = (const char*)vp + (size_t)kv0 * 2;
#pragma unroll
        for (int p = 0; p < 2; p++) {
            int off = p * 4096 + t * 16;
            int so = off ^ ssw;
            int row = so >> 7, colb = so & 127;
            __builtin_amdgcn_global_load_lds(
                (const __attribute__((address_space(1))) void*)(vg + (size_t)row * 4096 + colb),
                (__attribute__((address_space(3))) void*)((char*)&ldsV[buf][0] + off), 16, 0, 0);
        }
    };

    bf16x8 qfr[2][2];
#pragma unroll
    for (int mi = 0; mi < 2; mi++)
#pragma unroll
        for (int kk = 0; kk < 2; kk++)
            qfr[mi][kk] = *reinterpret_cast<const bf16x8*>(
                qp + (size_t)(q0 + mi * 16 + l15) * 64 + kk * 32 + lhi * 8);

    const int vq[2] = { vidb[q0 + l15], vidb[q0 + 16 + l15] };

    float mrow[2] = { -1e30f, -1e30f };
    f32x4 lacc[2];
    f32x4 oT[4][2];
#pragma unroll
    for (int mi = 0; mi < 2; mi++)
#pragma unroll
        for (int r = 0; r < 4; r++) lacc[mi][r] = 0.f;
#pragma unroll
    for (int nd = 0; nd < 4; nd++)
#pragma unroll
        for (int mi = 0; mi < 2; mi++)
#pragma unroll
            for (int r = 0; r < 4; r++) oT[nd][mi][r] = 0.f;

    stage(0, 0);
    __syncthreads();
    int cur = 0;

    for (int tt = 0; tt < S_ / 64; ++tt) {
        const int kv0 = tt * 64;
        if (tt < S_ / 64 - 1) stage(kv0 + 64, cur ^ 1);

        const u16* Kb = ldsK[cur];
        const u16* Vb = ldsV[cur];

        // ---- QK^T (swapped): sacc[ni][mi], lane holds S^T[k][q], log2 units ----
        f32x4 sacc[4][2];
        __builtin_amdgcn_s_setprio(1);
#pragma unroll
        for (int ni = 0; ni < 4; ni++) {
            int rowb = (ni * 16 + l15) * 128;
            bf16x8 kf0 = *reinterpret_cast<const bf16x8*>((const char*)Kb + ((rowb + lhi * 16) ^ sw));
            bf16x8 kf1 = *reinterpret_cast<const bf16x8*>((const char*)Kb + ((rowb + 64 + lhi * 16) ^ sw));
#pragma unroll
            for (int mi = 0; mi < 2; mi++) {
#pragma unroll
                for (int r = 0; r < 4; r++) sacc[ni][mi][r] = 0.f;
                sacc[ni][mi] = __builtin_amdgcn_mfma_f32_16x16x32_bf16(kf0, qfr[mi][0], sacc[ni][mi], 0, 0, 0);
                sacc[ni][mi] = __builtin_amdgcn_mfma_f32_16x16x32_bf16(kf1, qfr[mi][1], sacc[ni][mi], 0, 0, 0);
            }
        }
        __builtin_amdgcn_s_setprio(0);

        // ---- bias + mask (log2-scaled), folded: per score = cmp+cndmask+add ----
        i32x4 vkq[4];
        float base_c[4][4], base_s[4][4];
#pragma unroll
        for (int ni = 0; ni < 4; ni++) {
            vkq[ni] = *reinterpret_cast<const i32x4*>(vidb + kv0 + ni * 16 + lhi * 4);
            f32x4 mm = *reinterpret_cast<const f32x4*>(mkb + kv0 + ni * 16 + lhi * 4);
#pragma unroll
            for (int r = 0; r < 4; r++) {
                float md = (1.0f - mm[r]) * -1.44269504e9f;
                base_c[ni][r] = md + uc;
                base_s[ni][r] = md + us;
            }
        }
#pragma unroll
        for (int mi = 0; mi < 2; mi++)
#pragma unroll
            for (int ni = 0; ni < 4; ni++)
#pragma unroll
                for (int r = 0; r < 4; r++)
                    sacc[ni][mi][r] += (vkq[ni][r] == vq[mi]) ? base_s[ni][r] : base_c[ni][r];

        // ---- online softmax in log2 domain, defer-max; row-sum deferred to MFMA ----
        bf16x4 pb[2][4];
#pragma unroll
        for (int mi = 0; mi < 2; mi++) {
            float pm = max3v(sacc[0][mi][0], sacc[0][mi][1], sacc[0][mi][2]);
            pm = max3v(pm, sacc[0][mi][3], sacc[1][mi][0]);
            pm = max3v(pm, sacc[1][mi][1], sacc[1][mi][2]);
            pm = max3v(pm, sacc[1][mi][3], sacc[2][mi][0]);
            pm = max3v(pm, sacc[2][mi][1], sacc[2][mi][2]);
            pm = max3v(pm, sacc[2][mi][3], sacc[3][mi][0]);
            pm = max3v(pm, sacc[3][mi][1], sacc[3][mi][2]);
            pm = fmaxf(pm, sacc[3][mi][3]);
            pm = fmaxf(pm, __shfl_xor(pm, 16));
            pm = fmaxf(pm, __shfl_xor(pm, 32));
            if (!__all(pm <= mrow[mi] + 8.f)) {
                float mnew = fmaxf(mrow[mi], pm);
                float alpha = exp2v(mrow[mi] - mnew);
                mrow[mi] = mnew;
#pragma unroll
                for (int r = 0; r < 4; r++) lacc[mi][r] *= alpha;
#pragma unroll
                for (int nd = 0; nd < 4; nd++)
#pragma unroll
                    for (int r = 0; r < 4; r++) oT[nd][mi][r] *= alpha;
            }
#pragma unroll
            for (int ni = 0; ni < 4; ni++) {
                float p0 = exp2v(sacc[ni][mi][0] - mrow[mi]);
                float p1 = exp2v(sacc[ni][mi][1] - mrow[mi]);
                float p2 = exp2v(sacc[ni][mi][2] - mrow[mi]);
                float p3 = exp2v(sacc[ni][mi][3] - mrow[mi]);
                union { u32 u[2]; bf16x4 h; } uu;
                uu.u[0] = cvt_pk_bf16(p0, p1);
                uu.u[1] = cvt_pk_bf16(p2, p3);
                pb[mi][ni] = uu.h;
            }
        }

        // ---- PV + row-sum (both on matrix pipe): O^T += V^T·P ; l += 1^T·P ----
        __builtin_amdgcn_s_setprio(1);
#pragma unroll
        for (int mi = 0; mi < 2; mi++)
#pragma unroll
            for (int ni = 0; ni < 4; ni++)
                lacc[mi] = __builtin_amdgcn_mfma_f32_16x16x16bf16_1k(ones, pb[mi][ni], lacc[mi], 0, 0, 0);
#pragma unroll
        for (int nd = 0; nd < 4; nd++) {
            int rowb = (nd * 16 + l15) * 128;
            bf16x4 vf[4];
#pragma unroll
            for (int ni = 0; ni < 4; ni++)
                vf[ni] = *reinterpret_cast<const bf16x4*>((const char*)Vb + ((rowb + ni * 32 + lhi * 8) ^ sw));
#pragma unroll
            for (int mi = 0; mi < 2; mi++)
#pragma unroll
                for (int ni = 0; ni < 4; ni++)
                    oT[nd][mi] = __builtin_amdgcn_mfma_f32_16x16x16bf16_1k(vf[ni], pb[mi][ni], oT[nd][mi], 0, 0, 0);
        }
        __builtin_amdgcn_s_setprio(0);

        __syncthreads();
        cur ^= 1;
    }

#pragma unroll
    for (int mi = 0; mi < 2; mi++) {
        float inv = 1.0f / lacc[mi][0];     // col-sum replicated across regs; col = l15 = this lane's q
        size_t rowb = (size_t)(b * S_ + q0 + mi * 16 + l15) * D_;
#pragma unroll
        for (int nd = 0; nd < 4; nd++) {
            uint2 st;
            st.x = cvt_pk_bf16(oT[nd][mi][0] * inv, oT[nd][mi][1] * inv);
            st.y = cvt_pk_bf16(oT[nd][mi][2] * inv, oT[nd][mi][3] * inv);
            *reinterpret_cast<uint2*>(o + rowb + hh * 64 + nd * 16 + lhi * 4) = st;
        }
    }
}

// ---------------------------------------------------------------- LayerNorm: hb = LN(hb + t)*g + be  (bf16 in/out, 4 rows/block)
__global__ __launch_bounds__(256)
void ln_kernel(u16* hb, const u16* __restrict__ tb,
               const float* __restrict__ g, const float* __restrict__ be)
{
    const int row = blockIdx.x * 4 + (threadIdx.x >> 6);
    const int lane = threadIdx.x & 63;
    u16* hp = hb + (size_t)row * D_ + lane * 8;
    const u16* tp = tb + (size_t)row * D_ + lane * 8;
    bf16x8 a = *reinterpret_cast<const bf16x8*>(hp);
    bf16x8 c = *reinterpret_cast<const bf16x8*>(tp);
    float x[8];
    float s = 0.f, s2 = 0.f;
#pragma unroll
    for (int j = 0; j < 8; j++) {
        x[j] = bf2f((u16)a[j]) + bf2f((u16)c[j]);
        s += x[j]; s2 += x[j] * x[j];
    }
#pragma unroll
    for (int m = 1; m <= 32; m <<= 1) { s += __shfl_xor(s, m); s2 += __shfl_xor(s2, m); }
    float mean = s * (1.0f / 512.0f);
    float var = s2 * (1.0f / 512.0f) - mean * mean;
    float rstd = rsqrtf(var + 1e-5f);
    const float* gp = g + lane * 8;
    const float* bp = be + lane * 8;
    bf16x8 ov;
#pragma unroll
    for (int j = 0; j < 8; j++)
        ov[j] = (short)f2bf((x[j] - mean) * rstd * gp[j] + bp[j]);
    *reinterpret_cast<bf16x8*>(hp) = ov;
}

// ---------------------------------------------------------------- head: out(f32) = hb(bf16) @ Wh + bh  (N=32)
__global__ __launch_bounds__(256)
void head_kernel(const u16* __restrict__ hb, const float* __restrict__ Wh,
                 const float* __restrict__ bhv, float* __restrict__ out)
{
    const int t = threadIdx.x;
    const int p = t & 31, sub = t >> 5;
    const int row = blockIdx.x * 8 + sub;
    const u16* hp = hb + (size_t)row * D_;
    float acc = 0.f;
#pragma unroll 4
    for (int k0 = 0; k0 < D_; k0 += 8) {
        bf16x8 hv = *reinterpret_cast<const bf16x8*>(hp + k0);
#pragma unroll
        for (int j = 0; j < 8; j++)
            acc = fmaf(bf2f((u16)hv[j]), Wh[(size_t)(k0 + j) * 32 + p], acc);
    }
    out[(size_t)row * 32 + p] = acc + bhv[p];
}

// ---------------------------------------------------------------- launch
extern "C" void kernel_launch(void* const* d_in, const int* in_sizes, int n_in,
                              void* d_out, int out_size, void* d_ws, size_t ws_size,
                              hipStream_t stream)
{
    (void)in_sizes; (void)n_in; (void)out_size; (void)ws_size;
    const float* x     = (const float*)d_in[0];
    const int*   vid   = (const int*)d_in[1];
    const float* maskp = (const float*)d_in[2];
    const float* Wpe   = (const float*)d_in[3];
    const float* bpe   = (const float*)d_in[4];
    const float* Wq    = (const float*)d_in[5];
    const float* bq    = (const float*)d_in[6];
    const float* Wk    = (const float*)d_in[7];
    const float* bk    = (const float*)d_in[8];
    const float* Wv    = (const float*)d_in[9];
    const float* bv    = (const float*)d_in[10];
    const float* Wo    = (const float*)d_in[11];
    const float* bo    = (const float*)d_in[12];
    const float* usame = (const float*)d_in[13];
    const float* ucros = (const float*)d_in[14];
    const float* g1    = (const float*)d_in[15];
    const float* be1   = (const float*)d_in[16];
    const float* W1    = (const float*)d_in[17];
    const float* b1f   = (const float*)d_in[18];
    const float* W2    = (const float*)d_in[19];
    const float* b2f   = (const float*)d_in[20];
    const float* g2    = (const float*)d_in[21];
    const float* be2   = (const float*)d_in[22];
    const float* Whd   = (const float*)d_in[23];
    const float* bhd   = (const float*)d_in[24];

    constexpr size_t MB = 1024ull * 1024ull;
    char* ws = (char*)d_ws;
    u16*   hb   = (u16*)(ws + 0);          // 8 MB
    u16*   qbb  = (u16*)(ws + 8 * MB);     // 8 MB [b,h,s,64], pre-scaled by QSC_
    u16*   kbb  = (u16*)(ws + 16 * MB);    // 8 MB [b,h,s,64]
    u16*   vf16 = (u16*)(ws + 24 * MB);    // 8 MB [row][512]
    u16*   vtb  = (u16*)(ws + 32 * MB);    // 8 MB [b,h,d,s]
    u16*   ob   = (u16*)(ws + 40 * MB);    // 8 MB
    u16*   tb   = (u16*)(ws + 48 * MB);    // 8 MB
    u16*   fb   = (u16*)(ws + 56 * MB);    // 32 MB
    u16*   xb   = (u16*)(ws + 88 * MB);    // 0.5 MB
    float* rc   = (float*)(ws + 89 * MB);
    float* rs   = (float*)(ws + 89 * MB + 262144);
    float* bqkv = (float*)(ws + 90 * MB);
    u16*   wpe_t = (u16*)(ws + 91 * MB);
    u16*   wbase = (u16*)(ws + 92 * MB);   // per layer 3145728 u16 (6MB)

    auto qkvt = [&](int l) { return wbase + (size_t)l * 3145728; };
    auto wot  = [&](int l) { return qkvt(l) + 786432; };
    auto w1t  = [&](int l) { return qkvt(l) + 1048576; };
    auto w2t  = [&](int l) { return qkvt(l) + 2097152; };

    // prep (2 dispatches)
    wtrans_all<<<6160, 256, 0, stream>>>(Wpe, Wq, Wk, Wv, Wo, W1, W2, wpe_t, wbase);
    misc_prep<<<524, 256, 0, stream>>>(x, xb, bq, bk, bv, bqkv, rc, rs);

    // embed: hb = bf16(x @ W_pe + b_pe)  (K=32, legacy path)
    gemm_kernel<0, 64, 0><<<dim3(8, 64), 256, 0, stream>>>(
        xb, wpe_t, bpe, hb, BS_, 512, 32, 32,
        (u16*)nullptr, (u16*)nullptr, (u16*)nullptr, (const float*)nullptr, (const float*)nullptr);

    for (int l = 0; l < L_; l++) {
        // fused QKV + rope + relayout
        gemm_db<0, 128, 1><<<dim3(12, 64), 256, 0, stream>>>(
            hb, qkvt(l), bqkv + l * 1536, (u16*)nullptr, BS_, 1536, 512, 512,
            qbb, kbb, vf16, rc, rs);
        vtrans_kernel<<<dim3(32, 32), 256, 0, stream>>>(vf16, vtb);
        attn_kernel<<<512, 256, 0, stream>>>(qbb, kbb, vtb, vid, maskp,
                                             usame + l * H_, ucros + l * H_, ob);
        gemm_db<0, 64, 0><<<dim3(8, 64), 256, 0, stream>>>(
            ob, wot(l), bo + l * 512, tb, BS_, 512, 512, 512,
            (u16*)nullptr, (u16*)nullptr, (u16*)nullptr, (const float*)nullptr, (const float*)nullptr);
        ln_kernel<<<2048, 256, 0, stream>>>(hb, tb, g1 + l * 512, be1 + l * 512);
        gemm_db<1, 128, 0><<<dim3(16, 64), 256, 0, stream>>>(
            hb, w1t(l), b1f + l * 2048, fb, BS_, 2048, 512, 512,
            (u16*)nullptr, (u16*)nullptr, (u16*)nullptr, (const float*)nullptr, (const float*)nullptr);
        gemm_db<0, 64, 0><<<dim3(8, 64), 256, 0, stream>>>(
            fb, w2t(l), b2f + l * 512, tb, BS_, 512, 2048, 2048,
            (u16*)nullptr, (u16*)nullptr, (u16*)nullptr, (const float*)nullptr, (const float*)nullptr);
        ln_kernel<<<2048, 256, 0, stream>>>(hb, tb, g2 + l * 512, be2 + l * 512);
    }
    head_kernel<<<1024, 256, 0, stream>>>(hb, Whd, bhd, (float*)d_out);
}